// Round 1
// baseline (11313.985 us; speedup 1.0000x reference)
//
#include <hip/hip_runtime.h>
#include <math.h>

#define B_   4
#define L_   2048
#define H_   12
#define DH_  64
#define DM_  768
#define DFF_ 3072
#define NL_  12
#define M_   (B_*L_)
#define LN_EPS_  1e-5f
#define EMB_EPS_ 1e-12f
#define ATT_EPS_ 1e-6f

typedef unsigned short u16;
typedef __bf16 bf16x8 __attribute__((ext_vector_type(8)));
typedef float  f32x4  __attribute__((ext_vector_type(4)));

__device__ __forceinline__ u16 f2b(float f) {
  unsigned u = __builtin_bit_cast(unsigned, f);
  u += 0x7fffu + ((u >> 16) & 1u);
  return (u16)(u >> 16);
}
__device__ __forceinline__ float b2f(u16 s) {
  return __builtin_bit_cast(float, (unsigned)((unsigned)s << 16));
}
__device__ __forceinline__ float wredsum(float v) {
  #pragma unroll
  for (int o = 32; o > 0; o >>= 1) v += __shfl_xor(v, o, 64);
  return v;
}

// ---------------- weight f32 -> bf16 ----------------
__global__ __launch_bounds__(256) void cvt_bf16(const float* __restrict__ in,
                                                u16* __restrict__ out, int n4) {
  int i = blockIdx.x * 256 + threadIdx.x;
  if (i >= n4) return;
  float4 f = ((const float4*)in)[i];
  ushort4 o;
  o.x = f2b(f.x); o.y = f2b(f.y); o.z = f2b(f.z); o.w = f2b(f.w);
  ((ushort4*)out)[i] = o;
}

// ---------------- embedding + LN ----------------
__global__ __launch_bounds__(256) void embed_ln(
    const int* __restrict__ ids, const int* __restrict__ tts,
    const float* __restrict__ we, const float* __restrict__ pe,
    const float* __restrict__ te, const float* __restrict__ lw,
    const float* __restrict__ lb, float* __restrict__ x32, u16* __restrict__ xb)
{
  int row  = blockIdx.x * 4 + (threadIdx.x >> 6);
  int lane = threadIdx.x & 63;
  int l  = row & (L_ - 1);
  int id = ids[row];
  int tt = tts[row];
  const float* wr = we + (size_t)id * DM_;
  const float* pr = pe + (size_t)l  * DM_;
  const float* tr = te + (size_t)tt * DM_;
  float v[12]; float s = 0.f;
  #pragma unroll
  for (int j = 0; j < 12; j++) { int c = j*64 + lane; v[j] = wr[c] + pr[c] + tr[c]; s += v[j]; }
  s = wredsum(s);
  float m = s * (1.f/768.f);
  float q = 0.f;
  #pragma unroll
  for (int j = 0; j < 12; j++) { float d = v[j] - m; q += d*d; }
  q = wredsum(q);
  float rs = rsqrtf(q * (1.f/768.f) + EMB_EPS_);
  float* xo = x32 + (size_t)row * DM_;
  u16*   bo = xb  + (size_t)row * DM_;
  #pragma unroll
  for (int j = 0; j < 12; j++) {
    int c = j*64 + lane;
    float o = (v[j] - m) * rs * lw[c] + lb[c];
    xo[c] = o; bo[c] = f2b(o);
  }
}

// ---------------- residual + LN (in-place on x32, writes bf16 shadow) ----------------
__global__ __launch_bounds__(256) void ln_res(
    float* __restrict__ x32, const float* __restrict__ t32,
    const float* __restrict__ lw, const float* __restrict__ lb,
    u16* __restrict__ xb, float eps)
{
  int row  = blockIdx.x * 4 + (threadIdx.x >> 6);
  int lane = threadIdx.x & 63;
  float* xr = x32 + (size_t)row * DM_;
  const float* tr = t32 + (size_t)row * DM_;
  float v[12]; float s = 0.f;
  #pragma unroll
  for (int j = 0; j < 12; j++) { int c = j*64 + lane; v[j] = xr[c] + tr[c]; s += v[j]; }
  s = wredsum(s);
  float m = s * (1.f/768.f);
  float q = 0.f;
  #pragma unroll
  for (int j = 0; j < 12; j++) { float d = v[j] - m; q += d*d; }
  q = wredsum(q);
  float rs = rsqrtf(q * (1.f/768.f) + eps);
  u16* bo = xb + (size_t)row * DM_;
  #pragma unroll
  for (int j = 0; j < 12; j++) {
    int c = j*64 + lane;
    float o = (v[j] - m) * rs * lw[c] + lb[c];
    xr[c] = o; bo[c] = f2b(o);
  }
}

// ---------------- GEMM: C[M,N] = A[M,K] @ Bw[N,K]^T + bias ----------------
// EPI: 0 = bf16 out, 1 = elu+1 -> bf16, 2 = gelu(erf) -> bf16, 3 = f32 out
template<int EPI>
__global__ __launch_bounds__(256, 2)
void gemm_bt(const u16* __restrict__ A, const u16* __restrict__ Bw,
             const float* __restrict__ bias,
             u16* __restrict__ Co, float* __restrict__ Cf,
             int M, int N, int K)
{
  __shared__ alignas(16) u16 sA[128*40];
  __shared__ alignas(16) u16 sB[128*40];
  const int tid  = threadIdx.x;
  const int lane = tid & 63;
  const int wave = tid >> 6;
  const int wr = wave >> 1, wc = wave & 1;
  const int row0 = blockIdx.x * 128;
  const int col0 = blockIdx.y * 128;
  const int srow = tid >> 2;
  const int scol = (tid & 3) * 8;
  const int lr = lane & 15;
  const int lk = (lane >> 4) * 8;

  f32x4 zero = {0.f, 0.f, 0.f, 0.f};
  f32x4 acc[4][4];
  #pragma unroll
  for (int i = 0; i < 4; i++)
    #pragma unroll
    for (int j = 0; j < 4; j++) acc[i][j] = zero;

  const u16* Ap = A + (size_t)row0 * K;
  const u16* Bp = Bw + (size_t)col0 * K;

  for (int kt = 0; kt < K; kt += 32) {
    uint4 ra0 = *(const uint4*)(Ap + (size_t)(srow     ) * K + kt + scol);
    uint4 ra1 = *(const uint4*)(Ap + (size_t)(srow + 64) * K + kt + scol);
    uint4 rb0 = *(const uint4*)(Bp + (size_t)(srow     ) * K + kt + scol);
    uint4 rb1 = *(const uint4*)(Bp + (size_t)(srow + 64) * K + kt + scol);
    __syncthreads();
    *(uint4*)(sA + (srow     )*40 + scol) = ra0;
    *(uint4*)(sA + (srow + 64)*40 + scol) = ra1;
    *(uint4*)(sB + (srow     )*40 + scol) = rb0;
    *(uint4*)(sB + (srow + 64)*40 + scol) = rb1;
    __syncthreads();
    bf16x8 af[4], bv[4];
    #pragma unroll
    for (int m = 0; m < 4; m++) af[m] = *(const bf16x8*)(sA + (wr*64 + m*16 + lr)*40 + lk);
    #pragma unroll
    for (int n = 0; n < 4; n++) bv[n] = *(const bf16x8*)(sB + (wc*64 + n*16 + lr)*40 + lk);
    #pragma unroll
    for (int m = 0; m < 4; m++)
      #pragma unroll
      for (int n = 0; n < 4; n++)
        acc[m][n] = __builtin_amdgcn_mfma_f32_16x16x32_bf16(af[m], bv[n], acc[m][n], 0, 0, 0);
  }

  #pragma unroll
  for (int m = 0; m < 4; m++) {
    const int row_b = row0 + wr*64 + m*16 + (lane >> 4) * 4;
    #pragma unroll
    for (int n = 0; n < 4; n++) {
      const int col = col0 + wc*64 + n*16 + lr;
      const float bvb = bias[col];
      #pragma unroll
      for (int r = 0; r < 4; r++) {
        float v = acc[m][n][r] + bvb;
        if constexpr (EPI == 1) v = v > 0.f ? v + 1.f : expf(v);      // elu(v)+1
        if constexpr (EPI == 2) v = 0.5f * v * (1.f + erff(v * 0.70710678118654752f));
        const size_t off = (size_t)(row_b + r) * N + col;
        if constexpr (EPI == 3) Cf[off] = v;
        else                    Co[off] = f2b(v);
      }
    }
  }
}

// ---------------- KV[m][d] = sum_s v[s][m]*K[s][d] ; Ksum[d] = sum_s K[s][d] ----------------
__global__ __launch_bounds__(256) void kv_kern(
    const u16* __restrict__ kb, const u16* __restrict__ vb,
    const float* __restrict__ mask, float* __restrict__ kv, float* __restrict__ ksum)
{
  __shared__ float sK[64*64];
  __shared__ float sV[64*64];
  int bh = blockIdx.x;
  int b = bh / H_, h = bh % H_;
  int s0 = blockIdx.y * 256;
  int t = threadIdx.x;
  int m  = t >> 2;
  int d0 = (t & 3) * 16;
  float acc[16];
  #pragma unroll
  for (int i = 0; i < 16; i++) acc[i] = 0.f;
  float ks = 0.f;

  for (int ss = 0; ss < 256; ss += 64) {
    __syncthreads();
    #pragma unroll
    for (int r = 0; r < 2; r++) {
      int idx = r*256 + t;
      int sr = idx >> 3;
      int c  = (idx & 7) * 8;
      int sg = s0 + ss + sr;
      size_t base = ((size_t)(b*L_ + sg)) * DM_ + h*DH_ + c;
      uint4 kk = *(const uint4*)(kb + base);
      uint4 vv = *(const uint4*)(vb + base);
      float mk = mask[b*L_ + sg];
      const u16* kp = (const u16*)&kk;
      const u16* vp = (const u16*)&vv;
      #pragma unroll
      for (int j = 0; j < 8; j++) {
        sK[sr*64 + c + j] = b2f(kp[j]) * mk;
        sV[sr*64 + c + j] = b2f(vp[j]);
      }
    }
    __syncthreads();
    #pragma unroll
    for (int s = 0; s < 64; s++) {
      float vm = sV[s*64 + m];
      #pragma unroll
      for (int i4 = 0; i4 < 4; i4++) {
        float4 kk = *(const float4*)(sK + s*64 + d0 + i4*4);
        acc[i4*4+0] += vm * kk.x; acc[i4*4+1] += vm * kk.y;
        acc[i4*4+2] += vm * kk.z; acc[i4*4+3] += vm * kk.w;
      }
    }
    if (t < 64) {
      #pragma unroll
      for (int s = 0; s < 64; s++) ks += sK[s*64 + t];
    }
  }
  #pragma unroll
  for (int i = 0; i < 16; i++) atomicAdd(&kv[(size_t)bh*4096 + m*64 + d0 + i], acc[i]);
  if (t < 64) atomicAdd(&ksum[bh*64 + t], ks);
}

// ---------------- a[l,h,m] = Z * sum_d Q[l,h,d]*KV[h,m,d] ----------------
__global__ __launch_bounds__(256) void attn_av(
    const u16* __restrict__ qb, const float* __restrict__ kv,
    const float* __restrict__ ksum, u16* __restrict__ ab)
{
  __shared__ float sKV[64*64];
  __shared__ float sKs[64];
  __shared__ alignas(16) u16 sQ[128*72];
  int bh = blockIdx.x;
  int b = bh / H_, h = bh % H_;
  int l0 = blockIdx.y * 128;
  int t = threadIdx.x;
  for (int i = t; i < 4096; i += 256) sKV[i] = kv[(size_t)bh*4096 + i];
  if (t < 64) sKs[t] = ksum[bh*64 + t];
  #pragma unroll
  for (int r = 0; r < 4; r++) {
    int idx = r*256 + t;
    int s = idx >> 3;
    int c = (idx & 7) * 8;
    *(uint4*)(sQ + s*72 + c) =
        *(const uint4*)(qb + ((size_t)(b*L_ + l0 + s)) * DM_ + h*DH_ + c);
  }
  __syncthreads();
  int lrow = t >> 1;
  int mh = (t & 1) * 32;
  float q[64];
  #pragma unroll
  for (int d = 0; d < 64; d++) q[d] = b2f(sQ[lrow*72 + d]);
  float zd = 0.f;
  #pragma unroll
  for (int d = 0; d < 64; d++) zd += q[d] * sKs[d];
  float z = 1.f / (zd + ATT_EPS_);
  const float4* kv4 = (const float4*)sKV;
  float acc[32];
  #pragma unroll
  for (int i = 0; i < 32; i++) {
    float av = 0.f;
    #pragma unroll
    for (int d4 = 0; d4 < 16; d4++) {
      float4 kk = kv4[(mh + i)*16 + d4];
      av += q[d4*4+0]*kk.x + q[d4*4+1]*kk.y + q[d4*4+2]*kk.z + q[d4*4+3]*kk.w;
    }
    acc[i] = av;
  }
  u16* ao = ab + ((size_t)(b*L_ + l0 + lrow)) * DM_ + h*DH_ + mh;
  #pragma unroll
  for (int i = 0; i < 32; i++) ao[i] = f2b(acc[i] * z);
}

// ---------------- final copy ----------------
__global__ __launch_bounds__(256) void copyf4(const float4* __restrict__ in,
                                              float4* __restrict__ out, int n4) {
  int i = blockIdx.x * 256 + threadIdx.x;
  if (i < n4) out[i] = in[i];
}

extern "C" void kernel_launch(void* const* d_in, const int* in_sizes, int n_in,
                              void* d_out, int out_size, void* d_ws, size_t ws_size,
                              hipStream_t stream)
{
  const int*   ids  = (const int*)d_in[0];
  const float* mask = (const float*)d_in[1];
  const int*   tts  = (const int*)d_in[2];
  const float* we   = (const float*)d_in[3];
  const float* pe   = (const float*)d_in[4];
  const float* te   = (const float*)d_in[5];
  const float* elw  = (const float*)d_in[6];
  const float* elb  = (const float*)d_in[7];
  const float* Wq   = (const float*)d_in[8];
  const float* bq   = (const float*)d_in[9];
  const float* Wk   = (const float*)d_in[10];
  const float* bk   = (const float*)d_in[11];
  const float* Wv   = (const float*)d_in[12];
  const float* bv   = (const float*)d_in[13];
  const float* Wo   = (const float*)d_in[14];
  const float* bo   = (const float*)d_in[15];
  const float* l1w  = (const float*)d_in[16];
  const float* l1b  = (const float*)d_in[17];
  const float* W1   = (const float*)d_in[18];
  const float* b1   = (const float*)d_in[19];
  const float* W2   = (const float*)d_in[20];
  const float* b2   = (const float*)d_in[21];
  const float* l2w  = (const float*)d_in[22];
  const float* l2b  = (const float*)d_in[23];

  char* p = (char*)d_ws;
  auto alloc = [&](size_t n) -> char* {
    char* r = p; p += (n + 255) & ~(size_t)255; return r;
  };
  const size_t SQ = (size_t)NL_ * DM_ * DM_;   // 7,077,888
  const size_t SF = (size_t)NL_ * DFF_ * DM_;  // 28,311,552
  u16*  wqb = (u16*)alloc(SQ * 2);
  u16*  wkb = (u16*)alloc(SQ * 2);
  u16*  wvb = (u16*)alloc(SQ * 2);
  u16*  wob = (u16*)alloc(SQ * 2);
  u16*  w1b = (u16*)alloc(SF * 2);
  u16*  w2b = (u16*)alloc(SF * 2);
  float* x32 = (float*)alloc((size_t)M_ * DM_ * 4);
  float* t32 = (float*)alloc((size_t)M_ * DM_ * 4);
  u16*  xb   = (u16*)alloc((size_t)M_ * DM_ * 2);
  u16*  qbuf = (u16*)alloc((size_t)M_ * DM_ * 2);
  u16*  kbuf = (u16*)alloc((size_t)M_ * DM_ * 2);
  u16*  vbuf = (u16*)alloc((size_t)M_ * DM_ * 2);
  u16*  abuf = (u16*)alloc((size_t)M_ * DM_ * 2);
  u16*  ybuf = (u16*)alloc((size_t)M_ * DFF_ * 2);
  float* kvb = (float*)alloc((size_t)(B_*H_*DH_*DH_ + B_*H_*DH_) * 4);
  float* ksm = kvb + (size_t)B_*H_*DH_*DH_;

  // weight conversion (every call; no caching allowed)
  cvt_bf16<<<(int)(SQ/4/256), 256, 0, stream>>>(Wq, wqb, (int)(SQ/4));
  cvt_bf16<<<(int)(SQ/4/256), 256, 0, stream>>>(Wk, wkb, (int)(SQ/4));
  cvt_bf16<<<(int)(SQ/4/256), 256, 0, stream>>>(Wv, wvb, (int)(SQ/4));
  cvt_bf16<<<(int)(SQ/4/256), 256, 0, stream>>>(Wo, wob, (int)(SQ/4));
  cvt_bf16<<<(int)(SF/4/256), 256, 0, stream>>>(W1, w1b, (int)(SF/4));
  cvt_bf16<<<(int)(SF/4/256), 256, 0, stream>>>(W2, w2b, (int)(SF/4));

  embed_ln<<<M_/4, 256, 0, stream>>>(ids, tts, we, pe, te, elw, elb, x32, xb);

  for (int il = 0; il < NL_; ++il) {
    const u16* wq = wqb + (size_t)il * DM_ * DM_;
    const u16* wk = wkb + (size_t)il * DM_ * DM_;
    const u16* wv = wvb + (size_t)il * DM_ * DM_;
    const u16* wo = wob + (size_t)il * DM_ * DM_;
    const u16* w1 = w1b + (size_t)il * DFF_ * DM_;
    const u16* w2 = w2b + (size_t)il * DFF_ * DM_;
    const float* bql = bq + (size_t)il * DM_;
    const float* bkl = bk + (size_t)il * DM_;
    const float* bvl = bv + (size_t)il * DM_;
    const float* bol = bo + (size_t)il * DM_;
    const float* b1l = b1 + (size_t)il * DFF_;
    const float* b2l = b2 + (size_t)il * DM_;

    gemm_bt<1><<<dim3(M_/128, DM_/128), 256, 0, stream>>>(xb, wq, bql, qbuf, nullptr, M_, DM_, DM_);
    gemm_bt<1><<<dim3(M_/128, DM_/128), 256, 0, stream>>>(xb, wk, bkl, kbuf, nullptr, M_, DM_, DM_);
    gemm_bt<0><<<dim3(M_/128, DM_/128), 256, 0, stream>>>(xb, wv, bvl, vbuf, nullptr, M_, DM_, DM_);

    hipMemsetAsync(kvb, 0, (size_t)(B_*H_*DH_*DH_ + B_*H_*DH_) * 4, stream);
    kv_kern<<<dim3(B_*H_, L_/256), 256, 0, stream>>>(kbuf, vbuf, mask, kvb, ksm);
    attn_av<<<dim3(B_*H_, L_/128), 256, 0, stream>>>(qbuf, kvb, ksm, abuf);

    gemm_bt<3><<<dim3(M_/128, DM_/128), 256, 0, stream>>>(abuf, wo, bol, nullptr, t32, M_, DM_, DM_);
    ln_res<<<M_/4, 256, 0, stream>>>(x32, t32, l1w + (size_t)il*DM_, l1b + (size_t)il*DM_, xb, LN_EPS_);

    gemm_bt<2><<<dim3(M_/128, DFF_/128), 256, 0, stream>>>(xb, w1, b1l, ybuf, nullptr, M_, DFF_, DM_);
    gemm_bt<3><<<dim3(M_/128, DM_/128), 256, 0, stream>>>(ybuf, w2, b2l, nullptr, t32, M_, DM_, DFF_);
    ln_res<<<M_/4, 256, 0, stream>>>(x32, t32, l2w + (size_t)il*DM_, l2b + (size_t)il*DM_, xb, LN_EPS_);
  }

  copyf4<<<(M_*DM_/4)/256, 256, 0, stream>>>((const float4*)x32, (float4*)d_out, M_*DM_/4);
}

// Round 2
// 4820.693 us; speedup vs baseline: 2.3470x; 2.3470x over previous
//
#include <hip/hip_runtime.h>
#include <math.h>

#define B_   4
#define L_   2048
#define H_   12
#define DH_  64
#define DM_  768
#define DFF_ 3072
#define NL_  12
#define M_   (B_*L_)
#define NCH_ 32
#define LN_EPS_  1e-5f
#define EMB_EPS_ 1e-12f
#define ATT_EPS_ 1e-6f

typedef unsigned short u16;
typedef __bf16 bf16x8 __attribute__((ext_vector_type(8)));
typedef float  f32x4  __attribute__((ext_vector_type(4)));

__device__ __forceinline__ u16 f2b(float f) {
  unsigned u = __builtin_bit_cast(unsigned, f);
  u += 0x7fffu + ((u >> 16) & 1u);
  return (u16)(u >> 16);
}
__device__ __forceinline__ float b2f(u16 s) {
  return __builtin_bit_cast(float, (unsigned)((unsigned)s << 16));
}
__device__ __forceinline__ float wredsum(float v) {
  #pragma unroll
  for (int o = 32; o > 0; o >>= 1) v += __shfl_xor(v, o, 64);
  return v;
}

// ---------------- weight f32 -> bf16 ----------------
__global__ __launch_bounds__(256) void cvt_bf16(const float* __restrict__ in,
                                                u16* __restrict__ out, int n4) {
  int i = blockIdx.x * 256 + threadIdx.x;
  if (i >= n4) return;
  float4 f = ((const float4*)in)[i];
  ushort4 o;
  o.x = f2b(f.x); o.y = f2b(f.y); o.z = f2b(f.z); o.w = f2b(f.w);
  ((ushort4*)out)[i] = o;
}

// ---------------- embedding + LN ----------------
__global__ __launch_bounds__(256) void embed_ln(
    const int* __restrict__ ids, const int* __restrict__ tts,
    const float* __restrict__ we, const float* __restrict__ pe,
    const float* __restrict__ te, const float* __restrict__ lw,
    const float* __restrict__ lb, float* __restrict__ x32, u16* __restrict__ xb)
{
  int row  = blockIdx.x * 4 + (threadIdx.x >> 6);
  int lane = threadIdx.x & 63;
  int l  = row & (L_ - 1);
  int id = ids[row];
  int tt = tts[row];
  const float* wr = we + (size_t)id * DM_;
  const float* pr = pe + (size_t)l  * DM_;
  const float* tr = te + (size_t)tt * DM_;
  float v[12]; float s = 0.f;
  #pragma unroll
  for (int j = 0; j < 12; j++) { int c = j*64 + lane; v[j] = wr[c] + pr[c] + tr[c]; s += v[j]; }
  s = wredsum(s);
  float m = s * (1.f/768.f);
  float q = 0.f;
  #pragma unroll
  for (int j = 0; j < 12; j++) { float d = v[j] - m; q += d*d; }
  q = wredsum(q);
  float rs = rsqrtf(q * (1.f/768.f) + EMB_EPS_);
  float* xo = x32 + (size_t)row * DM_;
  u16*   bo = xb  + (size_t)row * DM_;
  #pragma unroll
  for (int j = 0; j < 12; j++) {
    int c = j*64 + lane;
    float o = (v[j] - m) * rs * lw[c] + lb[c];
    xo[c] = o; bo[c] = f2b(o);
  }
}

// ---------------- residual + LN (in-place on x32, writes bf16 shadow) ----------------
__global__ __launch_bounds__(256) void ln_res(
    float* __restrict__ x32, const float* __restrict__ t32,
    const float* __restrict__ lw, const float* __restrict__ lb,
    u16* __restrict__ xb, float eps)
{
  int row  = blockIdx.x * 4 + (threadIdx.x >> 6);
  int lane = threadIdx.x & 63;
  float* xr = x32 + (size_t)row * DM_;
  const float* tr = t32 + (size_t)row * DM_;
  float v[12]; float s = 0.f;
  #pragma unroll
  for (int j = 0; j < 12; j++) { int c = j*64 + lane; v[j] = xr[c] + tr[c]; s += v[j]; }
  s = wredsum(s);
  float m = s * (1.f/768.f);
  float q = 0.f;
  #pragma unroll
  for (int j = 0; j < 12; j++) { float d = v[j] - m; q += d*d; }
  q = wredsum(q);
  float rs = rsqrtf(q * (1.f/768.f) + eps);
  u16* bo = xb + (size_t)row * DM_;
  #pragma unroll
  for (int j = 0; j < 12; j++) {
    int c = j*64 + lane;
    float o = (v[j] - m) * rs * lw[c] + lb[c];
    xr[c] = o; bo[c] = f2b(o);
  }
}

// ---------------- GEMM: C[M,N] = A[M,K] @ Bw[N,K]^T + bias ----------------
// EPI: 0 = bf16 out, 1 = elu+1 -> bf16, 2 = gelu(erf) -> bf16, 3 = f32 out
template<int EPI>
__global__ __launch_bounds__(256, 2)
void gemm_bt(const u16* __restrict__ A, const u16* __restrict__ Bw,
             const float* __restrict__ bias,
             u16* __restrict__ Co, float* __restrict__ Cf,
             int M, int N, int K)
{
  __shared__ alignas(16) u16 sA[128*40];
  __shared__ alignas(16) u16 sB[128*40];
  const int tid  = threadIdx.x;
  const int lane = tid & 63;
  const int wave = tid >> 6;
  const int wr = wave >> 1, wc = wave & 1;
  const int row0 = blockIdx.x * 128;
  const int col0 = blockIdx.y * 128;
  const int srow = tid >> 2;
  const int scol = (tid & 3) * 8;
  const int lr = lane & 15;
  const int lk = (lane >> 4) * 8;

  f32x4 zero = {0.f, 0.f, 0.f, 0.f};
  f32x4 acc[4][4];
  #pragma unroll
  for (int i = 0; i < 4; i++)
    #pragma unroll
    for (int j = 0; j < 4; j++) acc[i][j] = zero;

  const u16* Ap = A + (size_t)row0 * K;
  const u16* Bp = Bw + (size_t)col0 * K;

  for (int kt = 0; kt < K; kt += 32) {
    uint4 ra0 = *(const uint4*)(Ap + (size_t)(srow     ) * K + kt + scol);
    uint4 ra1 = *(const uint4*)(Ap + (size_t)(srow + 64) * K + kt + scol);
    uint4 rb0 = *(const uint4*)(Bp + (size_t)(srow     ) * K + kt + scol);
    uint4 rb1 = *(const uint4*)(Bp + (size_t)(srow + 64) * K + kt + scol);
    __syncthreads();
    *(uint4*)(sA + (srow     )*40 + scol) = ra0;
    *(uint4*)(sA + (srow + 64)*40 + scol) = ra1;
    *(uint4*)(sB + (srow     )*40 + scol) = rb0;
    *(uint4*)(sB + (srow + 64)*40 + scol) = rb1;
    __syncthreads();
    bf16x8 af[4], bv[4];
    #pragma unroll
    for (int m = 0; m < 4; m++) af[m] = *(const bf16x8*)(sA + (wr*64 + m*16 + lr)*40 + lk);
    #pragma unroll
    for (int n = 0; n < 4; n++) bv[n] = *(const bf16x8*)(sB + (wc*64 + n*16 + lr)*40 + lk);
    #pragma unroll
    for (int m = 0; m < 4; m++)
      #pragma unroll
      for (int n = 0; n < 4; n++)
        acc[m][n] = __builtin_amdgcn_mfma_f32_16x16x32_bf16(af[m], bv[n], acc[m][n], 0, 0, 0);
  }

  #pragma unroll
  for (int m = 0; m < 4; m++) {
    const int row_b = row0 + wr*64 + m*16 + (lane >> 4) * 4;
    #pragma unroll
    for (int n = 0; n < 4; n++) {
      const int col = col0 + wc*64 + n*16 + lr;
      const float bvb = bias[col];
      #pragma unroll
      for (int r = 0; r < 4; r++) {
        float v = acc[m][n][r] + bvb;
        if constexpr (EPI == 1) v = v > 0.f ? v + 1.f : expf(v);      // elu(v)+1
        if constexpr (EPI == 2) v = 0.5f * v * (1.f + erff(v * 0.70710678118654752f));
        const size_t off = (size_t)(row_b + r) * N + col;
        if constexpr (EPI == 3) Cf[off] = v;
        else                    Co[off] = f2b(v);
      }
    }
  }
}

// ---------------- KV stage 1: per-(bh, 64-seq-chunk) partial outer product ----------------
// kvp[bh][chunk][m*64+d] = sum_{s in chunk} V[s][m]*K[s][d];  ksp = per-chunk K column sums
__global__ __launch_bounds__(256) void kv_part(
    const u16* __restrict__ kb, const u16* __restrict__ vb,
    const float* __restrict__ mask, float* __restrict__ kvp, float* __restrict__ ksp)
{
  __shared__ float sK[64*64];
  __shared__ float sV[64*64];
  const int bh = blockIdx.x;
  const int b = bh / H_, h = bh % H_;
  const int s0 = blockIdx.y * 64;
  const int t = threadIdx.x;
  #pragma unroll
  for (int r = 0; r < 2; r++) {
    int idx = r*256 + t;
    int sr = idx >> 3;
    int c  = (idx & 7) * 8;
    int sg = s0 + sr;
    size_t base = ((size_t)(b*L_ + sg)) * DM_ + h*DH_ + c;
    uint4 kk = *(const uint4*)(kb + base);
    uint4 vv = *(const uint4*)(vb + base);
    float mk = mask[b*L_ + sg];
    const u16* kp = (const u16*)&kk;
    const u16* vp = (const u16*)&vv;
    #pragma unroll
    for (int j = 0; j < 8; j++) {
      sK[sr*64 + c + j] = b2f(kp[j]) * mk;
      sV[sr*64 + c + j] = b2f(vp[j]);
    }
  }
  __syncthreads();
  const int m0 = (t >> 4) * 4;   // 16 m-groups
  const int d0 = (t & 15) * 4;   // 16 d-groups
  float acc[4][4] = {{0.f}};
  float ks[4] = {0.f, 0.f, 0.f, 0.f};
  for (int s = 0; s < 64; s++) {
    float4 vm = *(const float4*)(sV + s*64 + m0);
    float4 kk = *(const float4*)(sK + s*64 + d0);
    float vmv[4] = {vm.x, vm.y, vm.z, vm.w};
    float kkv[4] = {kk.x, kk.y, kk.z, kk.w};
    #pragma unroll
    for (int i = 0; i < 4; i++)
      #pragma unroll
      for (int j = 0; j < 4; j++) acc[i][j] += vmv[i] * kkv[j];
    if (t < 16) { ks[0] += kkv[0]; ks[1] += kkv[1]; ks[2] += kkv[2]; ks[3] += kkv[3]; }
  }
  float* o = kvp + ((size_t)bh*NCH_ + blockIdx.y) * 4096;
  #pragma unroll
  for (int i = 0; i < 4; i++) {
    float4 w = {acc[i][0], acc[i][1], acc[i][2], acc[i][3]};
    *(float4*)(o + (m0 + i)*64 + d0) = w;
  }
  if (t < 16) {
    float* ko = ksp + ((size_t)bh*NCH_ + blockIdx.y) * 64;
    #pragma unroll
    for (int j = 0; j < 4; j++) ko[d0 + j] = ks[j];
  }
}

// ---------------- KV stage 2: reduce over chunks ----------------
__global__ __launch_bounds__(256) void kv_reduce(
    const float* __restrict__ kvp, const float* __restrict__ ksp,
    float* __restrict__ kv, float* __restrict__ ksum)
{
  const int bh = blockIdx.x;
  const int i = blockIdx.y * 256 + threadIdx.x;   // grid.y = 16 -> 4096
  float s = 0.f;
  #pragma unroll 8
  for (int c = 0; c < NCH_; c++) s += kvp[((size_t)bh*NCH_ + c)*4096 + i];
  kv[(size_t)bh*4096 + i] = s;
  if (blockIdx.y == 0 && threadIdx.x < 64) {
    float q = 0.f;
    #pragma unroll 8
    for (int c = 0; c < NCH_; c++) q += ksp[((size_t)bh*NCH_ + c)*64 + threadIdx.x];
    ksum[bh*64 + threadIdx.x] = q;
  }
}

// ---------------- a[l,h,m] = Z * sum_d Q[l,h,d]*KV[h,m,d] ----------------
__global__ __launch_bounds__(256) void attn_av(
    const u16* __restrict__ qb, const float* __restrict__ kv,
    const float* __restrict__ ksum, u16* __restrict__ ab)
{
  __shared__ float sKV[64*64];
  __shared__ float sKs[64];
  __shared__ alignas(16) u16 sQ[128*72];
  int bh = blockIdx.x;
  int b = bh / H_, h = bh % H_;
  int l0 = blockIdx.y * 128;
  int t = threadIdx.x;
  for (int i = t; i < 4096; i += 256) sKV[i] = kv[(size_t)bh*4096 + i];
  if (t < 64) sKs[t] = ksum[bh*64 + t];
  #pragma unroll
  for (int r = 0; r < 4; r++) {
    int idx = r*256 + t;
    int s = idx >> 3;
    int c = (idx & 7) * 8;
    *(uint4*)(sQ + s*72 + c) =
        *(const uint4*)(qb + ((size_t)(b*L_ + l0 + s)) * DM_ + h*DH_ + c);
  }
  __syncthreads();
  int lrow = t >> 1;
  int mh = (t & 1) * 32;
  float q[64];
  #pragma unroll
  for (int d = 0; d < 64; d++) q[d] = b2f(sQ[lrow*72 + d]);
  float zd = 0.f;
  #pragma unroll
  for (int d = 0; d < 64; d++) zd += q[d] * sKs[d];
  float z = 1.f / (zd + ATT_EPS_);
  const float4* kv4 = (const float4*)sKV;
  float acc[32];
  #pragma unroll
  for (int i = 0; i < 32; i++) {
    float av = 0.f;
    #pragma unroll
    for (int d4 = 0; d4 < 16; d4++) {
      float4 kk = kv4[(mh + i)*16 + d4];
      av += q[d4*4+0]*kk.x + q[d4*4+1]*kk.y + q[d4*4+2]*kk.z + q[d4*4+3]*kk.w;
    }
    acc[i] = av;
  }
  u16* ao = ab + ((size_t)(b*L_ + l0 + lrow)) * DM_ + h*DH_ + mh;
  #pragma unroll
  for (int i = 0; i < 32; i++) ao[i] = f2b(acc[i] * z);
}

// ---------------- final copy ----------------
__global__ __launch_bounds__(256) void copyf4(const float4* __restrict__ in,
                                              float4* __restrict__ out, int n4) {
  int i = blockIdx.x * 256 + threadIdx.x;
  if (i < n4) out[i] = in[i];
}

extern "C" void kernel_launch(void* const* d_in, const int* in_sizes, int n_in,
                              void* d_out, int out_size, void* d_ws, size_t ws_size,
                              hipStream_t stream)
{
  const int*   ids  = (const int*)d_in[0];
  const float* mask = (const float*)d_in[1];
  const int*   tts  = (const int*)d_in[2];
  const float* we   = (const float*)d_in[3];
  const float* pe   = (const float*)d_in[4];
  const float* te   = (const float*)d_in[5];
  const float* elw  = (const float*)d_in[6];
  const float* elb  = (const float*)d_in[7];
  const float* Wq   = (const float*)d_in[8];
  const float* bq   = (const float*)d_in[9];
  const float* Wk   = (const float*)d_in[10];
  const float* bk   = (const float*)d_in[11];
  const float* Wv   = (const float*)d_in[12];
  const float* bv   = (const float*)d_in[13];
  const float* Wo   = (const float*)d_in[14];
  const float* bo   = (const float*)d_in[15];
  const float* l1w  = (const float*)d_in[16];
  const float* l1b  = (const float*)d_in[17];
  const float* W1   = (const float*)d_in[18];
  const float* b1   = (const float*)d_in[19];
  const float* W2   = (const float*)d_in[20];
  const float* b2   = (const float*)d_in[21];
  const float* l2w  = (const float*)d_in[22];
  const float* l2b  = (const float*)d_in[23];

  char* p = (char*)d_ws;
  auto alloc = [&](size_t n) -> char* {
    char* r = p; p += (n + 255) & ~(size_t)255; return r;
  };
  const size_t SQ = (size_t)NL_ * DM_ * DM_;   // 7,077,888
  const size_t SF = (size_t)NL_ * DFF_ * DM_;  // 28,311,552
  u16*  wqb = (u16*)alloc(SQ * 2);
  u16*  wkb = (u16*)alloc(SQ * 2);
  u16*  wvb = (u16*)alloc(SQ * 2);
  u16*  wob = (u16*)alloc(SQ * 2);
  u16*  w1b = (u16*)alloc(SF * 2);
  u16*  w2b = (u16*)alloc(SF * 2);
  float* x32 = (float*)alloc((size_t)M_ * DM_ * 4);
  float* t32 = (float*)alloc((size_t)M_ * DM_ * 4);
  u16*  xb   = (u16*)alloc((size_t)M_ * DM_ * 2);
  u16*  qbuf = (u16*)alloc((size_t)M_ * DM_ * 2);
  u16*  kbuf = (u16*)alloc((size_t)M_ * DM_ * 2);
  u16*  vbuf = (u16*)alloc((size_t)M_ * DM_ * 2);
  u16*  abuf = (u16*)alloc((size_t)M_ * DM_ * 2);
  u16*  ybuf = (u16*)alloc((size_t)M_ * DFF_ * 2);
  float* kvb = (float*)alloc((size_t)(B_*H_*DH_*DH_ + B_*H_*DH_) * 4);
  float* ksm = kvb + (size_t)B_*H_*DH_*DH_;
  float* ksp = (float*)alloc((size_t)B_*H_*NCH_*DH_ * 4);
  // kv partials alias t32 (dead between ln_res of prev layer and Wo GEMM);
  // both are exactly 8192*768*4 = 48*32*4096*4 = 25,165,824 bytes.
  float* kvp = t32;

  // weight conversion (every call; no caching allowed)
  cvt_bf16<<<(int)(SQ/4/256), 256, 0, stream>>>(Wq, wqb, (int)(SQ/4));
  cvt_bf16<<<(int)(SQ/4/256), 256, 0, stream>>>(Wk, wkb, (int)(SQ/4));
  cvt_bf16<<<(int)(SQ/4/256), 256, 0, stream>>>(Wv, wvb, (int)(SQ/4));
  cvt_bf16<<<(int)(SQ/4/256), 256, 0, stream>>>(Wo, wob, (int)(SQ/4));
  cvt_bf16<<<(int)(SF/4/256), 256, 0, stream>>>(W1, w1b, (int)(SF/4));
  cvt_bf16<<<(int)(SF/4/256), 256, 0, stream>>>(W2, w2b, (int)(SF/4));

  embed_ln<<<M_/4, 256, 0, stream>>>(ids, tts, we, pe, te, elw, elb, x32, xb);

  for (int il = 0; il < NL_; ++il) {
    const u16* wq = wqb + (size_t)il * DM_ * DM_;
    const u16* wk = wkb + (size_t)il * DM_ * DM_;
    const u16* wv = wvb + (size_t)il * DM_ * DM_;
    const u16* wo = wob + (size_t)il * DM_ * DM_;
    const u16* w1 = w1b + (size_t)il * DFF_ * DM_;
    const u16* w2 = w2b + (size_t)il * DFF_ * DM_;
    const float* bql = bq + (size_t)il * DM_;
    const float* bkl = bk + (size_t)il * DM_;
    const float* bvl = bv + (size_t)il * DM_;
    const float* bol = bo + (size_t)il * DM_;
    const float* b1l = b1 + (size_t)il * DFF_;
    const float* b2l = b2 + (size_t)il * DM_;

    gemm_bt<1><<<dim3(M_/128, DM_/128), 256, 0, stream>>>(xb, wq, bql, qbuf, nullptr, M_, DM_, DM_);
    gemm_bt<1><<<dim3(M_/128, DM_/128), 256, 0, stream>>>(xb, wk, bkl, kbuf, nullptr, M_, DM_, DM_);
    gemm_bt<0><<<dim3(M_/128, DM_/128), 256, 0, stream>>>(xb, wv, bvl, vbuf, nullptr, M_, DM_, DM_);

    kv_part<<<dim3(B_*H_, NCH_), 256, 0, stream>>>(kbuf, vbuf, mask, kvp, ksp);
    kv_reduce<<<dim3(B_*H_, 16), 256, 0, stream>>>(kvp, ksp, kvb, ksm);
    attn_av<<<dim3(B_*H_, L_/128), 256, 0, stream>>>(qbuf, kvb, ksm, abuf);

    gemm_bt<3><<<dim3(M_/128, DM_/128), 256, 0, stream>>>(abuf, wo, bol, nullptr, t32, M_, DM_, DM_);
    ln_res<<<M_/4, 256, 0, stream>>>(x32, t32, l1w + (size_t)il*DM_, l1b + (size_t)il*DM_, xb, LN_EPS_);

    gemm_bt<2><<<dim3(M_/128, DFF_/128), 256, 0, stream>>>(xb, w1, b1l, ybuf, nullptr, M_, DFF_, DM_);
    gemm_bt<3><<<dim3(M_/128, DM_/128), 256, 0, stream>>>(ybuf, w2, b2l, nullptr, t32, M_, DM_, DFF_);
    ln_res<<<M_/4, 256, 0, stream>>>(x32, t32, l2w + (size_t)il*DM_, l2b + (size_t)il*DM_, xb, LN_EPS_);
  }

  copyf4<<<(M_*DM_/4)/256, 256, 0, stream>>>((const float4*)x32, (float4*)d_out, M_*DM_/4);
}

// Round 4
// 3810.658 us; speedup vs baseline: 2.9690x; 1.2651x over previous
//
#include <hip/hip_runtime.h>
#include <math.h>

#define B_   4
#define L_   2048
#define H_   12
#define DH_  64
#define DM_  768
#define DFF_ 3072
#define NL_  12
#define M_   (B_*L_)
#define NCH_ 32
#define QLD_ 2304            // fused QKV row stride
#define LN_EPS_  1e-5f
#define EMB_EPS_ 1e-12f
#define ATT_EPS_ 1e-6f

typedef unsigned short u16;
typedef __bf16 bf16x8 __attribute__((ext_vector_type(8)));
typedef float  f32x4  __attribute__((ext_vector_type(4)));

__device__ __forceinline__ u16 f2b(float f) {
  unsigned u = __builtin_bit_cast(unsigned, f);
  u += 0x7fffu + ((u >> 16) & 1u);
  return (u16)(u >> 16);
}
__device__ __forceinline__ float b2f(u16 s) {
  return __builtin_bit_cast(float, (unsigned)((unsigned)s << 16));
}
__device__ __forceinline__ float wredsum(float v) {
  #pragma unroll
  for (int o = 32; o > 0; o >>= 1) v += __shfl_xor(v, o, 64);
  return v;
}
// async global->LDS, 16B per lane; lds dest is wave-uniform base + lane*16
__device__ __forceinline__ void gld16(const void* g, void* l) {
  __builtin_amdgcn_global_load_lds(
      (const __attribute__((address_space(1))) void*)g,
      (__attribute__((address_space(3))) void*)l, 16, 0, 0);
}

// ---------------- weight f32 -> bf16 (layout-preserving) ----------------
__global__ __launch_bounds__(256) void cvt_bf16(const float* __restrict__ in,
                                                u16* __restrict__ out, int n4) {
  int i = blockIdx.x * 256 + threadIdx.x;
  if (i >= n4) return;
  float4 f = ((const float4*)in)[i];
  ushort4 o;
  o.x = f2b(f.x); o.y = f2b(f.y); o.z = f2b(f.z); o.w = f2b(f.w);
  ((ushort4*)out)[i] = o;
}

// ---------------- weight f32 -> bf16 into fused [NL][2304][768] at row offset ro ----------------
__global__ __launch_bounds__(256) void cvt_bf16_qkv(const float* __restrict__ in,
                                                    u16* __restrict__ out, int ro) {
  int i = blockIdx.x * 256 + threadIdx.x;   // over NL*768*768/4
  if (i >= NL_*DM_*DM_/4) return;
  int row = i / 192;            // global row (l*768 + r), 192 float4 per row
  int c4  = (i % 192) * 4;
  int l = row / DM_, r = row % DM_;
  float4 f = ((const float4*)in)[i];
  ushort4 o;
  o.x = f2b(f.x); o.y = f2b(f.y); o.z = f2b(f.z); o.w = f2b(f.w);
  *(ushort4*)(out + ((size_t)l*QLD_ + ro + r)*DM_ + c4) = o;
}

// ---------------- fused bias [NL][2304] ----------------
__global__ __launch_bounds__(256) void fuse_bias(const float* __restrict__ bq,
    const float* __restrict__ bk, const float* __restrict__ bv, float* __restrict__ out) {
  int i = blockIdx.x * 256 + threadIdx.x;
  if (i >= NL_*QLD_) return;
  int l = i / QLD_, r = i % QLD_;
  float v = r < DM_ ? bq[l*DM_ + r] : r < 2*DM_ ? bk[l*DM_ + r - DM_] : bv[l*DM_ + r - 2*DM_];
  out[i] = v;
}

// ---------------- embedding + LN ----------------
__global__ __launch_bounds__(256) void embed_ln(
    const int* __restrict__ ids, const int* __restrict__ tts,
    const float* __restrict__ we, const float* __restrict__ pe,
    const float* __restrict__ te, const float* __restrict__ lw,
    const float* __restrict__ lb, float* __restrict__ x32, u16* __restrict__ xb)
{
  int row  = blockIdx.x * 4 + (threadIdx.x >> 6);
  int lane = threadIdx.x & 63;
  int l  = row & (L_ - 1);
  int id = ids[row];
  int tt = tts[row];
  const float* wr = we + (size_t)id * DM_;
  const float* pr = pe + (size_t)l  * DM_;
  const float* tr = te + (size_t)tt * DM_;
  float v[12]; float s = 0.f;
  #pragma unroll
  for (int j = 0; j < 12; j++) { int c = j*64 + lane; v[j] = wr[c] + pr[c] + tr[c]; s += v[j]; }
  s = wredsum(s);
  float m = s * (1.f/768.f);
  float q = 0.f;
  #pragma unroll
  for (int j = 0; j < 12; j++) { float d = v[j] - m; q += d*d; }
  q = wredsum(q);
  float rs = rsqrtf(q * (1.f/768.f) + EMB_EPS_);
  float* xo = x32 + (size_t)row * DM_;
  u16*   bo = xb  + (size_t)row * DM_;
  #pragma unroll
  for (int j = 0; j < 12; j++) {
    int c = j*64 + lane;
    float o = (v[j] - m) * rs * lw[c] + lb[c];
    xo[c] = o; bo[c] = f2b(o);
  }
}

// ---------------- residual + LN ----------------
__global__ __launch_bounds__(256) void ln_res(
    float* __restrict__ x32, const float* __restrict__ t32,
    const float* __restrict__ lw, const float* __restrict__ lb,
    u16* __restrict__ xb, float eps)
{
  int row  = blockIdx.x * 4 + (threadIdx.x >> 6);
  int lane = threadIdx.x & 63;
  float* xr = x32 + (size_t)row * DM_;
  const float* tr = t32 + (size_t)row * DM_;
  float v[12]; float s = 0.f;
  #pragma unroll
  for (int j = 0; j < 12; j++) { int c = j*64 + lane; v[j] = xr[c] + tr[c]; s += v[j]; }
  s = wredsum(s);
  float m = s * (1.f/768.f);
  float q = 0.f;
  #pragma unroll
  for (int j = 0; j < 12; j++) { float d = v[j] - m; q += d*d; }
  q = wredsum(q);
  float rs = rsqrtf(q * (1.f/768.f) + eps);
  u16* bo = xb + (size_t)row * DM_;
  #pragma unroll
  for (int j = 0; j < 12; j++) {
    int c = j*64 + lane;
    float o = (v[j] - m) * rs * lw[c] + lb[c];
    xr[c] = o; bo[c] = f2b(o);
  }
}

// ---------------- GEMM (m97 structure): C[M,N] = A[M,K] @ Bw[N,K]^T + bias ----------------
// EPI: 0 = bf16 out, 2 = gelu(erf)->bf16, 3 = f32 out, 4 = QKV fused (elu+1 on cols<1536)
template<int EPI>
__global__ __launch_bounds__(256)
void gemm_gl(const u16* __restrict__ A, const u16* __restrict__ Bw,
             const float* __restrict__ bias,
             u16* __restrict__ Co, float* __restrict__ Cf,
             int M, int N, int K, int ldc)
{
  __shared__ alignas(16) u16 sA[128*32];
  __shared__ alignas(16) u16 sB[128*32];
  const int tid  = threadIdx.x;
  const int lane = tid & 63;
  const int w    = tid >> 6;
  const int wr = w >> 1, wc = w & 1;
  const int row0 = blockIdx.x * 128;
  const int col0 = blockIdx.y * 128;
  const int grow = tid >> 2;          // 0..63
  const int gcol = (tid & 3) * 8;
  const int lr = lane & 15;
  const int lk = (lane >> 4) * 8;

  const u16* Ap = A  + (size_t)(row0 + grow) * K + gcol;
  const u16* Bp = Bw + (size_t)(col0 + grow) * K + gcol;
  u16* sAw0 = sA + w*512;          // wave-uniform LDS bases (lane*16B added by HW)
  u16* sAw1 = sA + 2048 + w*512;
  u16* sBw0 = sB + w*512;
  u16* sBw1 = sB + 2048 + w*512;

  f32x4 acc[4][4];
  #pragma unroll
  for (int i = 0; i < 4; i++)
    #pragma unroll
    for (int j = 0; j < 4; j++) acc[i][j] = (f32x4){0.f,0.f,0.f,0.f};

  for (int kt = 0; kt < K; kt += 32) {
    gld16(Ap + kt,                  sAw0);
    gld16(Ap + kt + (size_t)64*K,   sAw1);
    gld16(Bp + kt,                  sBw0);
    gld16(Bp + kt + (size_t)64*K,   sBw1);
    __syncthreads();                 // drains vmcnt before barrier
    bf16x8 af[4], bv[4];
    #pragma unroll
    for (int m = 0; m < 4; m++) af[m] = *(const bf16x8*)(sA + (wr*64 + m*16 + lr)*32 + lk);
    #pragma unroll
    for (int n = 0; n < 4; n++) bv[n] = *(const bf16x8*)(sB + (wc*64 + n*16 + lr)*32 + lk);
    #pragma unroll
    for (int m = 0; m < 4; m++)
      #pragma unroll
      for (int n = 0; n < 4; n++)
        acc[m][n] = __builtin_amdgcn_mfma_f32_16x16x32_bf16(af[m], bv[n], acc[m][n], 0, 0, 0);
    __syncthreads();                 // reads done before next stage overwrites
  }

  #pragma unroll
  for (int m = 0; m < 4; m++) {
    const int row_b = row0 + wr*64 + m*16 + (lane >> 4) * 4;
    #pragma unroll
    for (int n = 0; n < 4; n++) {
      const int col = col0 + wc*64 + n*16 + lr;
      const float bvb = bias[col];
      #pragma unroll
      for (int r = 0; r < 4; r++) {
        float v = acc[m][n][r] + bvb;
        if constexpr (EPI == 4) { if (col < 2*DM_) v = v > 0.f ? v + 1.f : expf(v); }
        if constexpr (EPI == 2) v = 0.5f * v * (1.f + erff(v * 0.70710678118654752f));
        const size_t off = (size_t)(row_b + r) * ldc + col;
        if constexpr (EPI == 3) Cf[off] = v;
        else                    Co[off] = f2b(v);
      }
    }
  }
}

// ---------------- KV stage 1: per-(bh, 64-seq-chunk) partial outer product ----------------
__global__ __launch_bounds__(256) void kv_part(
    const u16* __restrict__ qkv, const float* __restrict__ mask,
    float* __restrict__ kvp, float* __restrict__ ksp)
{
  __shared__ float sK[64*64];
  __shared__ float sV[64*64];
  const int bh = blockIdx.x;
  const int b = bh / H_, h = bh % H_;
  const int s0 = blockIdx.y * 64;
  const int t = threadIdx.x;
  const u16* kb = qkv + DM_;
  const u16* vb = qkv + 2*DM_;
  #pragma unroll
  for (int r = 0; r < 2; r++) {
    int idx = r*256 + t;
    int sr = idx >> 3;
    int c  = (idx & 7) * 8;
    int sg = s0 + sr;
    size_t base = ((size_t)(b*L_ + sg)) * QLD_ + h*DH_ + c;
    uint4 kk = *(const uint4*)(kb + base);
    uint4 vv = *(const uint4*)(vb + base);
    float mk = mask[b*L_ + sg];
    const u16* kp = (const u16*)&kk;
    const u16* vp = (const u16*)&vv;
    #pragma unroll
    for (int j = 0; j < 8; j++) {
      sK[sr*64 + c + j] = b2f(kp[j]) * mk;
      sV[sr*64 + c + j] = b2f(vp[j]);
    }
  }
  __syncthreads();
  const int m0 = (t >> 4) * 4;
  const int d0 = (t & 15) * 4;
  float acc[4][4] = {{0.f}};
  float ks[4] = {0.f, 0.f, 0.f, 0.f};
  for (int s = 0; s < 64; s++) {
    float4 vm = *(const float4*)(sV + s*64 + m0);
    float4 kk = *(const float4*)(sK + s*64 + d0);
    float vmv[4] = {vm.x, vm.y, vm.z, vm.w};
    float kkv[4] = {kk.x, kk.y, kk.z, kk.w};
    #pragma unroll
    for (int i = 0; i < 4; i++)
      #pragma unroll
      for (int j = 0; j < 4; j++) acc[i][j] += vmv[i] * kkv[j];
    if (t < 16) { ks[0] += kkv[0]; ks[1] += kkv[1]; ks[2] += kkv[2]; ks[3] += kkv[3]; }
  }
  float* o = kvp + ((size_t)bh*NCH_ + blockIdx.y) * 4096;
  #pragma unroll
  for (int i = 0; i < 4; i++) {
    float4 wv = {acc[i][0], acc[i][1], acc[i][2], acc[i][3]};
    *(float4*)(o + (m0 + i)*64 + d0) = wv;
  }
  if (t < 16) {
    float* ko = ksp + ((size_t)bh*NCH_ + blockIdx.y) * 64;
    #pragma unroll
    for (int j = 0; j < 4; j++) ko[d0 + j] = ks[j];
  }
}

// ---------------- KV stage 2: reduce over chunks ----------------
__global__ __launch_bounds__(256) void kv_reduce(
    const float* __restrict__ kvp, const float* __restrict__ ksp,
    float* __restrict__ kv, float* __restrict__ ksum)
{
  const int bh = blockIdx.x;
  const int i = blockIdx.y * 256 + threadIdx.x;
  float s = 0.f;
  #pragma unroll 8
  for (int c = 0; c < NCH_; c++) s += kvp[((size_t)bh*NCH_ + c)*4096 + i];
  kv[(size_t)bh*4096 + i] = s;
  if (blockIdx.y == 0 && threadIdx.x < 64) {
    float q = 0.f;
    #pragma unroll 8
    for (int c = 0; c < NCH_; c++) q += ksp[((size_t)bh*NCH_ + c)*64 + threadIdx.x];
    ksum[bh*64 + threadIdx.x] = q;
  }
}

// ---------------- attn: a[l,h,m] = Z * sum_d Q[l,h,d]*KV[h,m,d] (MFMA) ----------------
__global__ __launch_bounds__(256) void attn_av(
    const u16* __restrict__ qkv, const float* __restrict__ kv,
    const float* __restrict__ ksum, u16* __restrict__ ab)
{
  __shared__ alignas(16) u16 sQ[128*72];
  __shared__ alignas(16) u16 sKV[64*72];
  __shared__ float sKs[64];
  __shared__ float sZ[128];
  const int bh = blockIdx.x;
  const int b = bh / H_, h = bh % H_;
  const int l0 = blockIdx.y * 128;
  const int t = threadIdx.x;
  const int lane = t & 63;
  const int w = t >> 6;
  // stage KV (f32 -> bf16)
  for (int i = t; i < 4096; i += 256)
    sKV[(i >> 6)*72 + (i & 63)] = f2b(kv[(size_t)bh*4096 + i]);
  if (t < 64) sKs[t] = ksum[bh*64 + t];
  // stage Q (bf16, from fused qkv)
  #pragma unroll
  for (int r = 0; r < 4; r++) {
    int idx = r*256 + t;
    int s = idx >> 3;
    int c = (idx & 7) * 8;
    *(uint4*)(sQ + s*72 + c) =
        *(const uint4*)(qkv + ((size_t)(b*L_ + l0 + s)) * QLD_ + h*DH_ + c);
  }
  __syncthreads();
  // Z per row: 2 threads/row
  {
    int row = t >> 1, half = t & 1;
    float zd = 0.f;
    #pragma unroll
    for (int ch = 0; ch < 4; ch++) {
      bf16x8 qv = *(const bf16x8*)(sQ + row*72 + half*32 + ch*8);
      #pragma unroll
      for (int j = 0; j < 8; j++) zd += (float)qv[j] * sKs[half*32 + ch*8 + j];
    }
    zd += __shfl_xor(zd, 1, 64);
    if (half == 0) sZ[row] = 1.f / (zd + ATT_EPS_);
  }
  // MFMA: wave w -> rows w*32..w*32+31, cols 0..63
  const int lr = lane & 15, lk = (lane >> 4) * 8;
  f32x4 acc[2][4];
  #pragma unroll
  for (int m = 0; m < 2; m++)
    #pragma unroll
    for (int n = 0; n < 4; n++) acc[m][n] = (f32x4){0.f,0.f,0.f,0.f};
  #pragma unroll
  for (int kk = 0; kk < 2; kk++) {
    bf16x8 af[2], bv[4];
    #pragma unroll
    for (int m = 0; m < 2; m++) af[m] = *(const bf16x8*)(sQ + (w*32 + m*16 + lr)*72 + kk*32 + lk);
    #pragma unroll
    for (int n = 0; n < 4; n++) bv[n] = *(const bf16x8*)(sKV + (n*16 + lr)*72 + kk*32 + lk);
    #pragma unroll
    for (int m = 0; m < 2; m++)
      #pragma unroll
      for (int n = 0; n < 4; n++)
        acc[m][n] = __builtin_amdgcn_mfma_f32_16x16x32_bf16(af[m], bv[n], acc[m][n], 0, 0, 0);
  }
  __syncthreads();   // sZ visible
  #pragma unroll
  for (int m = 0; m < 2; m++) {
    const int row_l = w*32 + m*16 + (lane >> 4) * 4;
    #pragma unroll
    for (int n = 0; n < 4; n++) {
      const int col = n*16 + lr;
      #pragma unroll
      for (int r = 0; r < 4; r++) {
        float v = acc[m][n][r] * sZ[row_l + r];
        ab[((size_t)(b*L_ + l0 + row_l + r)) * DM_ + h*DH_ + col] = f2b(v);
      }
    }
  }
}

// ---------------- final copy ----------------
__global__ __launch_bounds__(256) void copyf4(const float4* __restrict__ in,
                                              float4* __restrict__ out, int n4) {
  int i = blockIdx.x * 256 + threadIdx.x;
  if (i < n4) out[i] = in[i];
}

extern "C" void kernel_launch(void* const* d_in, const int* in_sizes, int n_in,
                              void* d_out, int out_size, void* d_ws, size_t ws_size,
                              hipStream_t stream)
{
  const int*   ids  = (const int*)d_in[0];
  const float* mask = (const float*)d_in[1];
  const int*   tts  = (const int*)d_in[2];
  const float* we   = (const float*)d_in[3];
  const float* pe   = (const float*)d_in[4];
  const float* te   = (const float*)d_in[5];
  const float* elw  = (const float*)d_in[6];
  const float* elb  = (const float*)d_in[7];
  const float* Wq   = (const float*)d_in[8];
  const float* bq   = (const float*)d_in[9];
  const float* Wk   = (const float*)d_in[10];
  const float* bk   = (const float*)d_in[11];
  const float* Wv   = (const float*)d_in[12];
  const float* bv   = (const float*)d_in[13];
  const float* Wo   = (const float*)d_in[14];
  const float* bo   = (const float*)d_in[15];
  const float* l1w  = (const float*)d_in[16];
  const float* l1b  = (const float*)d_in[17];
  const float* W1   = (const float*)d_in[18];
  const float* b1   = (const float*)d_in[19];
  const float* W2   = (const float*)d_in[20];
  const float* b2   = (const float*)d_in[21];
  const float* l2w  = (const float*)d_in[22];
  const float* l2b  = (const float*)d_in[23];

  char* p = (char*)d_ws;
  auto alloc = [&](size_t n) -> char* {
    char* r = p; p += (n + 255) & ~(size_t)255; return r;
  };
  const size_t SQ = (size_t)NL_ * DM_ * DM_;
  const size_t SF = (size_t)NL_ * DFF_ * DM_;
  u16*  wqkvb = (u16*)alloc((size_t)NL_ * QLD_ * DM_ * 2);
  u16*  wob   = (u16*)alloc(SQ * 2);
  u16*  w1b   = (u16*)alloc(SF * 2);
  u16*  w2b   = (u16*)alloc(SF * 2);
  float* bqkv = (float*)alloc((size_t)NL_ * QLD_ * 4);
  float* x32  = (float*)alloc((size_t)M_ * DM_ * 4);
  float* t32  = (float*)alloc((size_t)M_ * DM_ * 4);
  u16*  xb    = (u16*)alloc((size_t)M_ * DM_ * 2);
  u16*  qkv   = (u16*)alloc((size_t)M_ * QLD_ * 2);
  u16*  abuf  = (u16*)alloc((size_t)M_ * DM_ * 2);
  u16*  ybuf  = (u16*)alloc((size_t)M_ * DFF_ * 2);
  float* kvb  = (float*)alloc((size_t)(B_*H_*DH_*DH_ + B_*H_*DH_) * 4);
  float* ksm  = kvb + (size_t)B_*H_*DH_*DH_;
  float* ksp  = (float*)alloc((size_t)B_*H_*NCH_*DH_ * 4);
  // kv partials alias t32 (dead until the Wo GEMM): 8192*768*4 == 48*32*4096*4
  float* kvp  = t32;

  const int nq4 = (int)(SQ/4);
  cvt_bf16_qkv<<<(nq4+255)/256, 256, 0, stream>>>(Wq, wqkvb, 0);
  cvt_bf16_qkv<<<(nq4+255)/256, 256, 0, stream>>>(Wk, wqkvb, DM_);
  cvt_bf16_qkv<<<(nq4+255)/256, 256, 0, stream>>>(Wv, wqkvb, 2*DM_);
  cvt_bf16<<<nq4/256, 256, 0, stream>>>(Wo, wob, nq4);
  cvt_bf16<<<(int)(SF/4/256), 256, 0, stream>>>(W1, w1b, (int)(SF/4));
  cvt_bf16<<<(int)(SF/4/256), 256, 0, stream>>>(W2, w2b, (int)(SF/4));
  fuse_bias<<<(NL_*QLD_+255)/256, 256, 0, stream>>>(bq, bk, bv, bqkv);

  embed_ln<<<M_/4, 256, 0, stream>>>(ids, tts, we, pe, te, elw, elb, x32, xb);

  for (int il = 0; il < NL_; ++il) {
    const u16* wqkv = wqkvb + (size_t)il * QLD_ * DM_;
    const u16* wo = wob + (size_t)il * DM_ * DM_;
    const u16* w1 = w1b + (size_t)il * DFF_ * DM_;
    const u16* w2 = w2b + (size_t)il * DFF_ * DM_;

    gemm_gl<4><<<dim3(M_/128, QLD_/128), 256, 0, stream>>>(
        xb, wqkv, bqkv + (size_t)il*QLD_, qkv, nullptr, M_, QLD_, DM_, QLD_);

    kv_part<<<dim3(B_*H_, NCH_), 256, 0, stream>>>(qkv, mask, kvp, ksp);
    kv_reduce<<<dim3(B_*H_, 16), 256, 0, stream>>>(kvp, ksp, kvb, ksm);
    attn_av<<<dim3(B_*H_, L_/128), 256, 0, stream>>>(qkv, kvb, ksm, abuf);

    gemm_gl<3><<<dim3(M_/128, DM_/128), 256, 0, stream>>>(
        abuf, wo, bo + (size_t)il*DM_, nullptr, t32, M_, DM_, DM_, DM_);
    ln_res<<<M_/4, 256, 0, stream>>>(x32, t32, l1w + (size_t)il*DM_, l1b + (size_t)il*DM_, xb, LN_EPS_);

    gemm_gl<2><<<dim3(M_/128, DFF_/128), 256, 0, stream>>>(
        xb, w1, b1 + (size_t)il*DFF_, ybuf, nullptr, M_, DFF_, DM_, DFF_);
    gemm_gl<3><<<dim3(M_/128, DM_/128), 256, 0, stream>>>(
        ybuf, w2, b2 + (size_t)il*DM_, nullptr, t32, M_, DM_, DFF_, DM_);
    ln_res<<<M_/4, 256, 0, stream>>>(x32, t32, l2w + (size_t)il*DM_, l2b + (size_t)il*DM_, xb, LN_EPS_);
  }

  copyf4<<<(M_*DM_/4)/256, 256, 0, stream>>>((const float4*)x32, (float4*)d_out, M_*DM_/4);
}

// Round 5
// 3401.266 us; speedup vs baseline: 3.3264x; 1.1204x over previous
//
#include <hip/hip_runtime.h>
#include <math.h>

#define B_   4
#define L_   2048
#define H_   12
#define DH_  64
#define DM_  768
#define DFF_ 3072
#define NL_  12
#define M_   (B_*L_)
#define NCH_ 32
#define QLD_ 2304            // fused QKV row stride
#define LN_EPS_  1e-5f
#define EMB_EPS_ 1e-12f
#define ATT_EPS_ 1e-6f

typedef unsigned short u16;
typedef __bf16 bf16x8 __attribute__((ext_vector_type(8)));
typedef float  f32x4  __attribute__((ext_vector_type(4)));

__device__ __forceinline__ u16 f2b(float f) {
  unsigned u = __builtin_bit_cast(unsigned, f);
  u += 0x7fffu + ((u >> 16) & 1u);
  return (u16)(u >> 16);
}
__device__ __forceinline__ float b2f(u16 s) {
  return __builtin_bit_cast(float, (unsigned)((unsigned)s << 16));
}
__device__ __forceinline__ float wredsum(float v) {
  #pragma unroll
  for (int o = 32; o > 0; o >>= 1) v += __shfl_xor(v, o, 64);
  return v;
}
// async global->LDS, 16B per lane; lds dest is wave-uniform base + lane*16
__device__ __forceinline__ void gld16(const void* g, void* l) {
  __builtin_amdgcn_global_load_lds(
      (const __attribute__((address_space(1))) void*)g,
      (__attribute__((address_space(3))) void*)l, 16, 0, 0);
}

// ---------------- weight f32 -> bf16 (layout-preserving) ----------------
__global__ __launch_bounds__(256) void cvt_bf16(const float* __restrict__ in,
                                                u16* __restrict__ out, int n4) {
  int i = blockIdx.x * 256 + threadIdx.x;
  if (i >= n4) return;
  float4 f = ((const float4*)in)[i];
  ushort4 o;
  o.x = f2b(f.x); o.y = f2b(f.y); o.z = f2b(f.z); o.w = f2b(f.w);
  ((ushort4*)out)[i] = o;
}

// ---------------- weight f32 -> bf16 into fused [NL][2304][768] at row offset ro ----------------
__global__ __launch_bounds__(256) void cvt_bf16_qkv(const float* __restrict__ in,
                                                    u16* __restrict__ out, int ro) {
  int i = blockIdx.x * 256 + threadIdx.x;   // over NL*768*768/4
  if (i >= NL_*DM_*DM_/4) return;
  int row = i / 192;            // global row (l*768 + r), 192 float4 per row
  int c4  = (i % 192) * 4;
  int l = row / DM_, r = row % DM_;
  float4 f = ((const float4*)in)[i];
  ushort4 o;
  o.x = f2b(f.x); o.y = f2b(f.y); o.z = f2b(f.z); o.w = f2b(f.w);
  *(ushort4*)(out + ((size_t)l*QLD_ + ro + r)*DM_ + c4) = o;
}

// ---------------- fused bias [NL][2304] ----------------
__global__ __launch_bounds__(256) void fuse_bias(const float* __restrict__ bq,
    const float* __restrict__ bk, const float* __restrict__ bv, float* __restrict__ out) {
  int i = blockIdx.x * 256 + threadIdx.x;
  if (i >= NL_*QLD_) return;
  int l = i / QLD_, r = i % QLD_;
  float v = r < DM_ ? bq[l*DM_ + r] : r < 2*DM_ ? bk[l*DM_ + r - DM_] : bv[l*DM_ + r - 2*DM_];
  out[i] = v;
}

// ---------------- embedding + LN ----------------
__global__ __launch_bounds__(256) void embed_ln(
    const int* __restrict__ ids, const int* __restrict__ tts,
    const float* __restrict__ we, const float* __restrict__ pe,
    const float* __restrict__ te, const float* __restrict__ lw,
    const float* __restrict__ lb, float* __restrict__ x32, u16* __restrict__ xb)
{
  int row  = blockIdx.x * 4 + (threadIdx.x >> 6);
  int lane = threadIdx.x & 63;
  int l  = row & (L_ - 1);
  int id = ids[row];
  int tt = tts[row];
  const float* wr = we + (size_t)id * DM_;
  const float* pr = pe + (size_t)l  * DM_;
  const float* tr = te + (size_t)tt * DM_;
  float v[12]; float s = 0.f;
  #pragma unroll
  for (int j = 0; j < 12; j++) { int c = j*64 + lane; v[j] = wr[c] + pr[c] + tr[c]; s += v[j]; }
  s = wredsum(s);
  float m = s * (1.f/768.f);
  float q = 0.f;
  #pragma unroll
  for (int j = 0; j < 12; j++) { float d = v[j] - m; q += d*d; }
  q = wredsum(q);
  float rs = rsqrtf(q * (1.f/768.f) + EMB_EPS_);
  float* xo = x32 + (size_t)row * DM_;
  u16*   bo = xb  + (size_t)row * DM_;
  #pragma unroll
  for (int j = 0; j < 12; j++) {
    int c = j*64 + lane;
    float o = (v[j] - m) * rs * lw[c] + lb[c];
    xo[c] = o; bo[c] = f2b(o);
  }
}

// ---------------- residual + LN ----------------
__global__ __launch_bounds__(256) void ln_res(
    float* __restrict__ x32, const float* __restrict__ t32,
    const float* __restrict__ lw, const float* __restrict__ lb,
    u16* __restrict__ xb, float eps)
{
  int row  = blockIdx.x * 4 + (threadIdx.x >> 6);
  int lane = threadIdx.x & 63;
  float* xr = x32 + (size_t)row * DM_;
  const float* tr = t32 + (size_t)row * DM_;
  float v[12]; float s = 0.f;
  #pragma unroll
  for (int j = 0; j < 12; j++) { int c = j*64 + lane; v[j] = xr[c] + tr[c]; s += v[j]; }
  s = wredsum(s);
  float m = s * (1.f/768.f);
  float q = 0.f;
  #pragma unroll
  for (int j = 0; j < 12; j++) { float d = v[j] - m; q += d*d; }
  q = wredsum(q);
  float rs = rsqrtf(q * (1.f/768.f) + eps);
  u16* bo = xb + (size_t)row * DM_;
  #pragma unroll
  for (int j = 0; j < 12; j++) {
    int c = j*64 + lane;
    float o = (v[j] - m) * rs * lw[c] + lb[c];
    xr[c] = o; bo[c] = f2b(o);
  }
}

// ---------------- GEMM (m97 structure): C[M,N] = A[M,K] @ Bw[N,K]^T + bias ----------------
// EPI: 0 = bf16 out, 2 = gelu(erf)->bf16, 3 = f32 out, 4 = QKV fused (elu+1 on cols<1536)
template<int EPI>
__global__ __launch_bounds__(256)
void gemm_gl(const u16* __restrict__ A, const u16* __restrict__ Bw,
             const float* __restrict__ bias,
             u16* __restrict__ Co, float* __restrict__ Cf,
             int M, int N, int K, int ldc)
{
  __shared__ alignas(16) u16 sA[128*32];
  __shared__ alignas(16) u16 sB[128*32];
  const int tid  = threadIdx.x;
  const int lane = tid & 63;
  const int w    = tid >> 6;
  const int wr = w >> 1, wc = w & 1;
  const int row0 = blockIdx.x * 128;
  const int col0 = blockIdx.y * 128;
  const int grow = tid >> 2;          // 0..63
  const int gcol = (tid & 3) * 8;
  const int lr = lane & 15;
  const int lk = (lane >> 4) * 8;

  const u16* Ap = A  + (size_t)(row0 + grow) * K + gcol;
  const u16* Bp = Bw + (size_t)(col0 + grow) * K + gcol;
  u16* sAw0 = sA + w*512;          // wave-uniform LDS bases (lane*16B added by HW)
  u16* sAw1 = sA + 2048 + w*512;
  u16* sBw0 = sB + w*512;
  u16* sBw1 = sB + 2048 + w*512;

  f32x4 acc[4][4];
  #pragma unroll
  for (int i = 0; i < 4; i++)
    #pragma unroll
    for (int j = 0; j < 4; j++) acc[i][j] = (f32x4){0.f,0.f,0.f,0.f};

  for (int kt = 0; kt < K; kt += 32) {
    gld16(Ap + kt,                  sAw0);
    gld16(Ap + kt + (size_t)64*K,   sAw1);
    gld16(Bp + kt,                  sBw0);
    gld16(Bp + kt + (size_t)64*K,   sBw1);
    __syncthreads();                 // drains vmcnt before barrier
    bf16x8 af[4], bv[4];
    #pragma unroll
    for (int m = 0; m < 4; m++) af[m] = *(const bf16x8*)(sA + (wr*64 + m*16 + lr)*32 + lk);
    #pragma unroll
    for (int n = 0; n < 4; n++) bv[n] = *(const bf16x8*)(sB + (wc*64 + n*16 + lr)*32 + lk);
    #pragma unroll
    for (int m = 0; m < 4; m++)
      #pragma unroll
      for (int n = 0; n < 4; n++)
        acc[m][n] = __builtin_amdgcn_mfma_f32_16x16x32_bf16(af[m], bv[n], acc[m][n], 0, 0, 0);
    __syncthreads();                 // reads done before next stage overwrites
  }

  #pragma unroll
  for (int m = 0; m < 4; m++) {
    const int row_b = row0 + wr*64 + m*16 + (lane >> 4) * 4;
    #pragma unroll
    for (int n = 0; n < 4; n++) {
      const int col = col0 + wc*64 + n*16 + lr;
      const float bvb = bias[col];
      #pragma unroll
      for (int r = 0; r < 4; r++) {
        float v = acc[m][n][r] + bvb;
        if constexpr (EPI == 4) { if (col < 2*DM_) v = v > 0.f ? v + 1.f : expf(v); }
        if constexpr (EPI == 2) v = 0.5f * v * (1.f + erff(v * 0.70710678118654752f));
        const size_t off = (size_t)(row_b + r) * ldc + col;
        if constexpr (EPI == 3) Cf[off] = v;
        else                    Co[off] = f2b(v);
      }
    }
  }
}

// ---------------- skinny-N GEMM: BM=128, BN=64, BK=64, f32 out + bias ----------------
// For N=768 outputs (Wo, W2): grid (M/128, N/64) = 768 blocks -> ~3 blocks/CU.
// BK=64 halves barrier count; 128B row stride would be a 16-way bank conflict,
// so LDS uses an XOR swizzle: stored 16B-group c' = c ^ (row&7), realized by
// pre-swizzling the per-lane GLOBAL source col (linear gld16 dest, rule 21).
__global__ __launch_bounds__(256)
void gemm_n64(const u16* __restrict__ A, const u16* __restrict__ Bw,
              const float* __restrict__ bias, float* __restrict__ Cf,
              int M, int N, int K, int ldc)
{
  __shared__ alignas(16) u16 sA[128*64];
  __shared__ alignas(16) u16 sB[64*64];
  const int tid  = threadIdx.x;
  const int lane = tid & 63;
  const int w    = tid >> 6;
  const int row0 = blockIdx.x * 128;
  const int col0 = blockIdx.y * 64;
  const int lr = lane & 15;
  const int g  = lane >> 4;            // 16B-group within 64B quarter (0..3)
  const int srow = lane >> 3;          // 0..7 (row within an 8-row staging slab)
  // swizzled global source col (u16): original group = (lane&7) ^ (row&7), row&7==srow
  const int acol = (((lane & 7) ^ srow) * 8);

  f32x4 acc[2][4];
  #pragma unroll
  for (int i = 0; i < 2; i++)
    #pragma unroll
    for (int j = 0; j < 4; j++) acc[i][j] = (f32x4){0.f,0.f,0.f,0.f};

  const u16* ApA = A  + (size_t)(row0)*K;
  const u16* BpB = Bw + (size_t)(col0)*K;

  for (int kt = 0; kt < K; kt += 64) {
    #pragma unroll
    for (int j = 0; j < 4; j++)   // A: wave w stages rows [w*32 .. w*32+32)
      gld16(ApA + (size_t)(w*32 + j*8 + srow)*K + kt + acol, sA + (w*32 + j*8)*64);
    #pragma unroll
    for (int j = 0; j < 2; j++)   // B: wave w stages rows [w*16 .. w*16+16)
      gld16(BpB + (size_t)(w*16 + j*8 + srow)*K + kt + acol, sB + (w*16 + j*8)*64);
    __syncthreads();               // drains vmcnt before barrier
    #pragma unroll
    for (int kk = 0; kk < 2; kk++) {
      bf16x8 af[2], bv[4];
      #pragma unroll
      for (int m = 0; m < 2; m++) {
        const int R = w*32 + m*16 + lr;
        const int gg = (kk*4 + g) ^ (lr & 7);
        af[m] = *(const bf16x8*)(sA + R*64 + gg*8);
      }
      #pragma unroll
      for (int n = 0; n < 4; n++) {
        const int R = n*16 + lr;
        const int gg = (kk*4 + g) ^ (lr & 7);
        bv[n] = *(const bf16x8*)(sB + R*64 + gg*8);
      }
      #pragma unroll
      for (int m = 0; m < 2; m++)
        #pragma unroll
        for (int n = 0; n < 4; n++)
          acc[m][n] = __builtin_amdgcn_mfma_f32_16x16x32_bf16(af[m], bv[n], acc[m][n], 0, 0, 0);
    }
    __syncthreads();
  }

  #pragma unroll
  for (int m = 0; m < 2; m++) {
    const int row_b = row0 + w*32 + m*16 + (lane >> 4) * 4;
    #pragma unroll
    for (int n = 0; n < 4; n++) {
      const int col = col0 + n*16 + lr;
      const float bvb = bias[col];
      #pragma unroll
      for (int r = 0; r < 4; r++)
        Cf[(size_t)(row_b + r) * ldc + col] = acc[m][n][r] + bvb;
    }
  }
}

// ---------------- KV stage 1: per-(bh, 64-seq-chunk) partial outer product ----------------
__global__ __launch_bounds__(256) void kv_part(
    const u16* __restrict__ qkv, const float* __restrict__ mask,
    float* __restrict__ kvp, float* __restrict__ ksp)
{
  __shared__ float sK[64*64];
  __shared__ float sV[64*64];
  const int bh = blockIdx.x;
  const int b = bh / H_, h = bh % H_;
  const int s0 = blockIdx.y * 64;
  const int t = threadIdx.x;
  const u16* kb = qkv + DM_;
  const u16* vb = qkv + 2*DM_;
  #pragma unroll
  for (int r = 0; r < 2; r++) {
    int idx = r*256 + t;
    int sr = idx >> 3;
    int c  = (idx & 7) * 8;
    int sg = s0 + sr;
    size_t base = ((size_t)(b*L_ + sg)) * QLD_ + h*DH_ + c;
    uint4 kk = *(const uint4*)(kb + base);
    uint4 vv = *(const uint4*)(vb + base);
    float mk = mask[b*L_ + sg];
    const u16* kp = (const u16*)&kk;
    const u16* vp = (const u16*)&vv;
    #pragma unroll
    for (int j = 0; j < 8; j++) {
      sK[sr*64 + c + j] = b2f(kp[j]) * mk;
      sV[sr*64 + c + j] = b2f(vp[j]);
    }
  }
  __syncthreads();
  const int m0 = (t >> 4) * 4;
  const int d0 = (t & 15) * 4;
  float acc[4][4] = {{0.f}};
  float ks[4] = {0.f, 0.f, 0.f, 0.f};
  for (int s = 0; s < 64; s++) {
    float4 vm = *(const float4*)(sV + s*64 + m0);
    float4 kk = *(const float4*)(sK + s*64 + d0);
    float vmv[4] = {vm.x, vm.y, vm.z, vm.w};
    float kkv[4] = {kk.x, kk.y, kk.z, kk.w};
    #pragma unroll
    for (int i = 0; i < 4; i++)
      #pragma unroll
      for (int j = 0; j < 4; j++) acc[i][j] += vmv[i] * kkv[j];
    if (t < 16) { ks[0] += kkv[0]; ks[1] += kkv[1]; ks[2] += kkv[2]; ks[3] += kkv[3]; }
  }
  float* o = kvp + ((size_t)bh*NCH_ + blockIdx.y) * 4096;
  #pragma unroll
  for (int i = 0; i < 4; i++) {
    float4 wv = {acc[i][0], acc[i][1], acc[i][2], acc[i][3]};
    *(float4*)(o + (m0 + i)*64 + d0) = wv;
  }
  if (t < 16) {
    float* ko = ksp + ((size_t)bh*NCH_ + blockIdx.y) * 64;
    #pragma unroll
    for (int j = 0; j < 4; j++) ko[d0 + j] = ks[j];
  }
}

// ---------------- KV stage 2: reduce over chunks ----------------
__global__ __launch_bounds__(256) void kv_reduce(
    const float* __restrict__ kvp, const float* __restrict__ ksp,
    float* __restrict__ kv, float* __restrict__ ksum)
{
  const int bh = blockIdx.x;
  const int i = blockIdx.y * 256 + threadIdx.x;
  float s = 0.f;
  #pragma unroll 8
  for (int c = 0; c < NCH_; c++) s += kvp[((size_t)bh*NCH_ + c)*4096 + i];
  kv[(size_t)bh*4096 + i] = s;
  if (blockIdx.y == 0 && threadIdx.x < 64) {
    float q = 0.f;
    #pragma unroll 8
    for (int c = 0; c < NCH_; c++) q += ksp[((size_t)bh*NCH_ + c)*64 + threadIdx.x];
    ksum[bh*64 + threadIdx.x] = q;
  }
}

// ---------------- attn: a[l,h,m] = Z * sum_d Q[l,h,d]*KV[h,m,d] (MFMA) ----------------
__global__ __launch_bounds__(256) void attn_av(
    const u16* __restrict__ qkv, const float* __restrict__ kv,
    const float* __restrict__ ksum, u16* __restrict__ ab)
{
  __shared__ alignas(16) u16 sQ[128*72];
  __shared__ alignas(16) u16 sKV[64*72];
  __shared__ float sKs[64];
  __shared__ float sZ[128];
  const int bh = blockIdx.x;
  const int b = bh / H_, h = bh % H_;
  const int l0 = blockIdx.y * 128;
  const int t = threadIdx.x;
  const int lane = t & 63;
  const int w = t >> 6;
  // stage KV (f32 -> bf16)
  for (int i = t; i < 4096; i += 256)
    sKV[(i >> 6)*72 + (i & 63)] = f2b(kv[(size_t)bh*4096 + i]);
  if (t < 64) sKs[t] = ksum[bh*64 + t];
  // stage Q (bf16, from fused qkv)
  #pragma unroll
  for (int r = 0; r < 4; r++) {
    int idx = r*256 + t;
    int s = idx >> 3;
    int c = (idx & 7) * 8;
    *(uint4*)(sQ + s*72 + c) =
        *(const uint4*)(qkv + ((size_t)(b*L_ + l0 + s)) * QLD_ + h*DH_ + c);
  }
  __syncthreads();
  // Z per row: 2 threads/row
  {
    int row = t >> 1, half = t & 1;
    float zd = 0.f;
    #pragma unroll
    for (int ch = 0; ch < 4; ch++) {
      bf16x8 qv = *(const bf16x8*)(sQ + row*72 + half*32 + ch*8);
      #pragma unroll
      for (int j = 0; j < 8; j++) zd += (float)qv[j] * sKs[half*32 + ch*8 + j];
    }
    zd += __shfl_xor(zd, 1, 64);
    if (half == 0) sZ[row] = 1.f / (zd + ATT_EPS_);
  }
  // MFMA: wave w -> rows w*32..w*32+31, cols 0..63
  const int lr = lane & 15, lk = (lane >> 4) * 8;
  f32x4 acc[2][4];
  #pragma unroll
  for (int m = 0; m < 2; m++)
    #pragma unroll
    for (int n = 0; n < 4; n++) acc[m][n] = (f32x4){0.f,0.f,0.f,0.f};
  #pragma unroll
  for (int kk = 0; kk < 2; kk++) {
    bf16x8 af[2], bv[4];
    #pragma unroll
    for (int m = 0; m < 2; m++) af[m] = *(const bf16x8*)(sQ + (w*32 + m*16 + lr)*72 + kk*32 + lk);
    #pragma unroll
    for (int n = 0; n < 4; n++) bv[n] = *(const bf16x8*)(sKV + (n*16 + lr)*72 + kk*32 + lk);
    #pragma unroll
    for (int m = 0; m < 2; m++)
      #pragma unroll
      for (int n = 0; n < 4; n++)
        acc[m][n] = __builtin_amdgcn_mfma_f32_16x16x32_bf16(af[m], bv[n], acc[m][n], 0, 0, 0);
  }
  __syncthreads();   // sZ visible
  #pragma unroll
  for (int m = 0; m < 2; m++) {
    const int row_l = w*32 + m*16 + (lane >> 4) * 4;
    #pragma unroll
    for (int n = 0; n < 4; n++) {
      const int col = n*16 + lr;
      #pragma unroll
      for (int r = 0; r < 4; r++) {
        float v = acc[m][n][r] * sZ[row_l + r];
        ab[((size_t)(b*L_ + l0 + row_l + r)) * DM_ + h*DH_ + col] = f2b(v);
      }
    }
  }
}

// ---------------- final copy ----------------
__global__ __launch_bounds__(256) void copyf4(const float4* __restrict__ in,
                                              float4* __restrict__ out, int n4) {
  int i = blockIdx.x * 256 + threadIdx.x;
  if (i < n4) out[i] = in[i];
}

extern "C" void kernel_launch(void* const* d_in, const int* in_sizes, int n_in,
                              void* d_out, int out_size, void* d_ws, size_t ws_size,
                              hipStream_t stream)
{
  const int*   ids  = (const int*)d_in[0];
  const float* mask = (const float*)d_in[1];
  const int*   tts  = (const int*)d_in[2];
  const float* we   = (const float*)d_in[3];
  const float* pe   = (const float*)d_in[4];
  const float* te   = (const float*)d_in[5];
  const float* elw  = (const float*)d_in[6];
  const float* elb  = (const float*)d_in[7];
  const float* Wq   = (const float*)d_in[8];
  const float* bq   = (const float*)d_in[9];
  const float* Wk   = (const float*)d_in[10];
  const float* bk   = (const float*)d_in[11];
  const float* Wv   = (const float*)d_in[12];
  const float* bv   = (const float*)d_in[13];
  const float* Wo   = (const float*)d_in[14];
  const float* bo   = (const float*)d_in[15];
  const float* l1w  = (const float*)d_in[16];
  const float* l1b  = (const float*)d_in[17];
  const float* W1   = (const float*)d_in[18];
  const float* b1   = (const float*)d_in[19];
  const float* W2   = (const float*)d_in[20];
  const float* b2   = (const float*)d_in[21];
  const float* l2w  = (const float*)d_in[22];
  const float* l2b  = (const float*)d_in[23];

  char* p = (char*)d_ws;
  auto alloc = [&](size_t n) -> char* {
    char* r = p; p += (n + 255) & ~(size_t)255; return r;
  };
  const size_t SQ = (size_t)NL_ * DM_ * DM_;
  const size_t SF = (size_t)NL_ * DFF_ * DM_;
  u16*  wqkvb = (u16*)alloc((size_t)NL_ * QLD_ * DM_ * 2);
  u16*  wob   = (u16*)alloc(SQ * 2);
  u16*  w1b   = (u16*)alloc(SF * 2);
  u16*  w2b   = (u16*)alloc(SF * 2);
  float* bqkv = (float*)alloc((size_t)NL_ * QLD_ * 4);
  float* x32  = (float*)alloc((size_t)M_ * DM_ * 4);
  float* t32  = (float*)alloc((size_t)M_ * DM_ * 4);
  u16*  xb    = (u16*)alloc((size_t)M_ * DM_ * 2);
  u16*  qkv   = (u16*)alloc((size_t)M_ * QLD_ * 2);
  u16*  abuf  = (u16*)alloc((size_t)M_ * DM_ * 2);
  u16*  ybuf  = (u16*)alloc((size_t)M_ * DFF_ * 2);
  float* kvb  = (float*)alloc((size_t)(B_*H_*DH_*DH_ + B_*H_*DH_) * 4);
  float* ksm  = kvb + (size_t)B_*H_*DH_*DH_;
  float* ksp  = (float*)alloc((size_t)B_*H_*NCH_*DH_ * 4);
  // kv partials alias t32 (dead until the Wo GEMM): 8192*768*4 == 48*32*4096*4
  float* kvp  = t32;

  const int nq4 = (int)(SQ/4);
  cvt_bf16_qkv<<<(nq4+255)/256, 256, 0, stream>>>(Wq, wqkvb, 0);
  cvt_bf16_qkv<<<(nq4+255)/256, 256, 0, stream>>>(Wk, wqkvb, DM_);
  cvt_bf16_qkv<<<(nq4+255)/256, 256, 0, stream>>>(Wv, wqkvb, 2*DM_);
  cvt_bf16<<<nq4/256, 256, 0, stream>>>(Wo, wob, nq4);
  cvt_bf16<<<(int)(SF/4/256), 256, 0, stream>>>(W1, w1b, (int)(SF/4));
  cvt_bf16<<<(int)(SF/4/256), 256, 0, stream>>>(W2, w2b, (int)(SF/4));
  fuse_bias<<<(NL_*QLD_+255)/256, 256, 0, stream>>>(bq, bk, bv, bqkv);

  embed_ln<<<M_/4, 256, 0, stream>>>(ids, tts, we, pe, te, elw, elb, x32, xb);

  for (int il = 0; il < NL_; ++il) {
    const u16* wqkv = wqkvb + (size_t)il * QLD_ * DM_;
    const u16* wo = wob + (size_t)il * DM_ * DM_;
    const u16* w1 = w1b + (size_t)il * DFF_ * DM_;
    const u16* w2 = w2b + (size_t)il * DFF_ * DM_;

    gemm_gl<4><<<dim3(M_/128, QLD_/128), 256, 0, stream>>>(
        xb, wqkv, bqkv + (size_t)il*QLD_, qkv, nullptr, M_, QLD_, DM_, QLD_);

    kv_part<<<dim3(B_*H_, NCH_), 256, 0, stream>>>(qkv, mask, kvp, ksp);
    kv_reduce<<<dim3(B_*H_, 16), 256, 0, stream>>>(kvp, ksp, kvb, ksm);
    attn_av<<<dim3(B_*H_, L_/128), 256, 0, stream>>>(qkv, kvb, ksm, abuf);

    gemm_n64<<<dim3(M_/128, DM_/64), 256, 0, stream>>>(
        abuf, wo, bo + (size_t)il*DM_, t32, M_, DM_, DM_, DM_);
    ln_res<<<M_/4, 256, 0, stream>>>(x32, t32, l1w + (size_t)il*DM_, l1b + (size_t)il*DM_, xb, LN_EPS_);

    gemm_gl<2><<<dim3(M_/128, DFF_/128), 256, 0, stream>>>(
        xb, w1, b1 + (size_t)il*DFF_, ybuf, nullptr, M_, DFF_, DM_, DFF_);
    gemm_n64<<<dim3(M_/128, DM_/64), 256, 0, stream>>>(
        ybuf, w2, b2 + (size_t)il*DM_, t32, M_, DM_, DFF_, DM_);
    ln_res<<<M_/4, 256, 0, stream>>>(x32, t32, l2w + (size_t)il*DM_, l2b + (size_t)il*DM_, xb, LN_EPS_);
  }

  copyf4<<<(M_*DM_/4)/256, 256, 0, stream>>>((const float4*)x32, (float4*)d_out, M_*DM_/4);
}

// Round 6
// 3227.017 us; speedup vs baseline: 3.5060x; 1.0540x over previous
//
#include <hip/hip_runtime.h>
#include <math.h>

#define B_   4
#define L_   2048
#define H_   12
#define DH_  64
#define DM_  768
#define DFF_ 3072
#define NL_  12
#define M_   (B_*L_)
#define NCH_ 32
#define QLD_ 2304            // fused QKV row stride
#define LN_EPS_  1e-5f
#define EMB_EPS_ 1e-12f
#define ATT_EPS_ 1e-6f

typedef unsigned short u16;
typedef __bf16 bf16x8 __attribute__((ext_vector_type(8)));
typedef float  f32x4  __attribute__((ext_vector_type(4)));

__device__ __forceinline__ u16 f2b(float f) {
  unsigned u = __builtin_bit_cast(unsigned, f);
  u += 0x7fffu + ((u >> 16) & 1u);
  return (u16)(u >> 16);
}
__device__ __forceinline__ float b2f(u16 s) {
  return __builtin_bit_cast(float, (unsigned)((unsigned)s << 16));
}
__device__ __forceinline__ float wredsum(float v) {
  #pragma unroll
  for (int o = 32; o > 0; o >>= 1) v += __shfl_xor(v, o, 64);
  return v;
}
// async global->LDS, 16B per lane; lds dest is wave-uniform base + lane*16
__device__ __forceinline__ void gld16(const void* g, void* l) {
  __builtin_amdgcn_global_load_lds(
      (const __attribute__((address_space(1))) void*)g,
      (__attribute__((address_space(3))) void*)l, 16, 0, 0);
}

// ---------------- weight f32 -> bf16 (layout-preserving) ----------------
__global__ __launch_bounds__(256) void cvt_bf16(const float* __restrict__ in,
                                                u16* __restrict__ out, int n4) {
  int i = blockIdx.x * 256 + threadIdx.x;
  if (i >= n4) return;
  float4 f = ((const float4*)in)[i];
  ushort4 o;
  o.x = f2b(f.x); o.y = f2b(f.y); o.z = f2b(f.z); o.w = f2b(f.w);
  ((ushort4*)out)[i] = o;
}

// ---------------- weight f32 -> bf16 into fused [NL][2304][768] at row offset ro ----------------
__global__ __launch_bounds__(256) void cvt_bf16_qkv(const float* __restrict__ in,
                                                    u16* __restrict__ out, int ro) {
  int i = blockIdx.x * 256 + threadIdx.x;   // over NL*768*768/4
  if (i >= NL_*DM_*DM_/4) return;
  int row = i / 192;            // global row (l*768 + r), 192 float4 per row
  int c4  = (i % 192) * 4;
  int l = row / DM_, r = row % DM_;
  float4 f = ((const float4*)in)[i];
  ushort4 o;
  o.x = f2b(f.x); o.y = f2b(f.y); o.z = f2b(f.z); o.w = f2b(f.w);
  *(ushort4*)(out + ((size_t)l*QLD_ + ro + r)*DM_ + c4) = o;
}

// ---------------- fused bias [NL][2304] ----------------
__global__ __launch_bounds__(256) void fuse_bias(const float* __restrict__ bq,
    const float* __restrict__ bk, const float* __restrict__ bv, float* __restrict__ out) {
  int i = blockIdx.x * 256 + threadIdx.x;
  if (i >= NL_*QLD_) return;
  int l = i / QLD_, r = i % QLD_;
  float v = r < DM_ ? bq[l*DM_ + r] : r < 2*DM_ ? bk[l*DM_ + r - DM_] : bv[l*DM_ + r - 2*DM_];
  out[i] = v;
}

// ---------------- embedding + LN ----------------
__global__ __launch_bounds__(256) void embed_ln(
    const int* __restrict__ ids, const int* __restrict__ tts,
    const float* __restrict__ we, const float* __restrict__ pe,
    const float* __restrict__ te, const float* __restrict__ lw,
    const float* __restrict__ lb, float* __restrict__ x32, u16* __restrict__ xb)
{
  int row  = blockIdx.x * 4 + (threadIdx.x >> 6);
  int lane = threadIdx.x & 63;
  int l  = row & (L_ - 1);
  int id = ids[row];
  int tt = tts[row];
  const float* wr = we + (size_t)id * DM_;
  const float* pr = pe + (size_t)l  * DM_;
  const float* tr = te + (size_t)tt * DM_;
  float v[12]; float s = 0.f;
  #pragma unroll
  for (int j = 0; j < 12; j++) { int c = j*64 + lane; v[j] = wr[c] + pr[c] + tr[c]; s += v[j]; }
  s = wredsum(s);
  float m = s * (1.f/768.f);
  float q = 0.f;
  #pragma unroll
  for (int j = 0; j < 12; j++) { float d = v[j] - m; q += d*d; }
  q = wredsum(q);
  float rs = rsqrtf(q * (1.f/768.f) + EMB_EPS_);
  float* xo = x32 + (size_t)row * DM_;
  u16*   bo = xb  + (size_t)row * DM_;
  #pragma unroll
  for (int j = 0; j < 12; j++) {
    int c = j*64 + lane;
    float o = (v[j] - m) * rs * lw[c] + lb[c];
    xo[c] = o; bo[c] = f2b(o);
  }
}

// ---------------- residual + LN ----------------
__global__ __launch_bounds__(256) void ln_res(
    float* __restrict__ x32, const float* __restrict__ t32,
    const float* __restrict__ lw, const float* __restrict__ lb,
    u16* __restrict__ xb, float eps)
{
  int row  = blockIdx.x * 4 + (threadIdx.x >> 6);
  int lane = threadIdx.x & 63;
  float* xr = x32 + (size_t)row * DM_;
  const float* tr = t32 + (size_t)row * DM_;
  float v[12]; float s = 0.f;
  #pragma unroll
  for (int j = 0; j < 12; j++) { int c = j*64 + lane; v[j] = xr[c] + tr[c]; s += v[j]; }
  s = wredsum(s);
  float m = s * (1.f/768.f);
  float q = 0.f;
  #pragma unroll
  for (int j = 0; j < 12; j++) { float d = v[j] - m; q += d*d; }
  q = wredsum(q);
  float rs = rsqrtf(q * (1.f/768.f) + eps);
  u16* bo = xb + (size_t)row * DM_;
  #pragma unroll
  for (int j = 0; j < 12; j++) {
    int c = j*64 + lane;
    float o = (v[j] - m) * rs * lw[c] + lb[c];
    xr[c] = o; bo[c] = f2b(o);
  }
}

// ---------------- GEMM: C[M,N] = A[M,K] @ Bw[N,K]^T + bias ----------------
// BM=BN=128, BK=64, both-sides XOR swizzle (linear gld16 dest, pre-swizzled
// global source group (lane&7)^(row&7), read group (kk*4+g)^(lr&7)).
// EPI: 0 = bf16 out, 2 = gelu(erf)->bf16, 3 = f32 out, 4 = QKV fused (elu+1 on cols<1536)
template<int EPI>
__global__ __launch_bounds__(256)
void gemm_gl(const u16* __restrict__ A, const u16* __restrict__ Bw,
             const float* __restrict__ bias,
             u16* __restrict__ Co, float* __restrict__ Cf,
             int M, int N, int K, int ldc)
{
  __shared__ alignas(16) u16 sA[128*64];
  __shared__ alignas(16) u16 sB[128*64];
  const int tid  = threadIdx.x;
  const int lane = tid & 63;
  const int w    = tid >> 6;
  const int wr = w >> 1, wc = w & 1;
  const int row0 = blockIdx.x * 128;
  const int col0 = blockIdx.y * 128;
  const int lr = lane & 15;
  const int g  = lane >> 4;            // 16B-group (0..3) within a 32-col k-slice
  const int srow = lane >> 3;          // row within 8-row staging slab
  const int acol = (((lane & 7) ^ srow) * 8);  // swizzled global source col (u16)

  f32x4 acc[4][4];
  #pragma unroll
  for (int i = 0; i < 4; i++)
    #pragma unroll
    for (int j = 0; j < 4; j++) acc[i][j] = (f32x4){0.f,0.f,0.f,0.f};

  const u16* Ap = A  + (size_t)row0 * K;
  const u16* Bp = Bw + (size_t)col0 * K;

  for (int kt = 0; kt < K; kt += 64) {
    #pragma unroll
    for (int j = 0; j < 4; j++) {   // wave w stages A rows [w*32, w*32+32) and B likewise
      gld16(Ap + (size_t)(w*32 + j*8 + srow)*K + kt + acol, sA + (w*32 + j*8)*64);
      gld16(Bp + (size_t)(w*32 + j*8 + srow)*K + kt + acol, sB + (w*32 + j*8)*64);
    }
    __syncthreads();                 // drains vmcnt before barrier
    #pragma unroll
    for (int kk = 0; kk < 2; kk++) {
      const int gg = ((kk*4 + g) ^ (lr & 7)) * 8;
      bf16x8 af[4], bv[4];
      #pragma unroll
      for (int m = 0; m < 4; m++) af[m] = *(const bf16x8*)(sA + (wr*64 + m*16 + lr)*64 + gg);
      #pragma unroll
      for (int n = 0; n < 4; n++) bv[n] = *(const bf16x8*)(sB + (wc*64 + n*16 + lr)*64 + gg);
      #pragma unroll
      for (int m = 0; m < 4; m++)
        #pragma unroll
        for (int n = 0; n < 4; n++)
          acc[m][n] = __builtin_amdgcn_mfma_f32_16x16x32_bf16(af[m], bv[n], acc[m][n], 0, 0, 0);
    }
    __syncthreads();                 // reads done before next stage overwrites
  }

  #pragma unroll
  for (int m = 0; m < 4; m++) {
    const int row_b = row0 + wr*64 + m*16 + (lane >> 4) * 4;
    #pragma unroll
    for (int n = 0; n < 4; n++) {
      const int col = col0 + wc*64 + n*16 + lr;
      const float bvb = bias[col];
      #pragma unroll
      for (int r = 0; r < 4; r++) {
        float v = acc[m][n][r] + bvb;
        if constexpr (EPI == 4) { if (col < 2*DM_) v = v > 0.f ? v + 1.f : expf(v); }
        if constexpr (EPI == 2) v = 0.5f * v * (1.f + erff(v * 0.70710678118654752f));
        const size_t off = (size_t)(row_b + r) * ldc + col;
        if constexpr (EPI == 3) Cf[off] = v;
        else                    Co[off] = f2b(v);
      }
    }
  }
}

// ---------------- skinny-N GEMM: BM=128, BN=64, BK=64, f32 out + bias ----------------
__global__ __launch_bounds__(256)
void gemm_n64(const u16* __restrict__ A, const u16* __restrict__ Bw,
              const float* __restrict__ bias, float* __restrict__ Cf,
              int M, int N, int K, int ldc)
{
  __shared__ alignas(16) u16 sA[128*64];
  __shared__ alignas(16) u16 sB[64*64];
  const int tid  = threadIdx.x;
  const int lane = tid & 63;
  const int w    = tid >> 6;
  const int row0 = blockIdx.x * 128;
  const int col0 = blockIdx.y * 64;
  const int lr = lane & 15;
  const int g  = lane >> 4;
  const int srow = lane >> 3;
  const int acol = (((lane & 7) ^ srow) * 8);

  f32x4 acc[2][4];
  #pragma unroll
  for (int i = 0; i < 2; i++)
    #pragma unroll
    for (int j = 0; j < 4; j++) acc[i][j] = (f32x4){0.f,0.f,0.f,0.f};

  const u16* ApA = A  + (size_t)(row0)*K;
  const u16* BpB = Bw + (size_t)(col0)*K;

  for (int kt = 0; kt < K; kt += 64) {
    #pragma unroll
    for (int j = 0; j < 4; j++)
      gld16(ApA + (size_t)(w*32 + j*8 + srow)*K + kt + acol, sA + (w*32 + j*8)*64);
    #pragma unroll
    for (int j = 0; j < 2; j++)
      gld16(BpB + (size_t)(w*16 + j*8 + srow)*K + kt + acol, sB + (w*16 + j*8)*64);
    __syncthreads();
    #pragma unroll
    for (int kk = 0; kk < 2; kk++) {
      bf16x8 af[2], bv[4];
      #pragma unroll
      for (int m = 0; m < 2; m++) {
        const int R = w*32 + m*16 + lr;
        const int gg = (kk*4 + g) ^ (lr & 7);
        af[m] = *(const bf16x8*)(sA + R*64 + gg*8);
      }
      #pragma unroll
      for (int n = 0; n < 4; n++) {
        const int R = n*16 + lr;
        const int gg = (kk*4 + g) ^ (lr & 7);
        bv[n] = *(const bf16x8*)(sB + R*64 + gg*8);
      }
      #pragma unroll
      for (int m = 0; m < 2; m++)
        #pragma unroll
        for (int n = 0; n < 4; n++)
          acc[m][n] = __builtin_amdgcn_mfma_f32_16x16x32_bf16(af[m], bv[n], acc[m][n], 0, 0, 0);
    }
    __syncthreads();
  }

  #pragma unroll
  for (int m = 0; m < 2; m++) {
    const int row_b = row0 + w*32 + m*16 + (lane >> 4) * 4;
    #pragma unroll
    for (int n = 0; n < 4; n++) {
      const int col = col0 + n*16 + lr;
      const float bvb = bias[col];
      #pragma unroll
      for (int r = 0; r < 4; r++)
        Cf[(size_t)(row_b + r) * ldc + col] = acc[m][n][r] + bvb;
    }
  }
}

// ---------------- KV stage 1: per-(bh, 64-seq-chunk) partial outer product ----------------
__global__ __launch_bounds__(256) void kv_part(
    const u16* __restrict__ qkv, const float* __restrict__ mask,
    float* __restrict__ kvp, float* __restrict__ ksp)
{
  __shared__ float sK[64*64];
  __shared__ float sV[64*64];
  const int bh = blockIdx.x;
  const int b = bh / H_, h = bh % H_;
  const int s0 = blockIdx.y * 64;
  const int t = threadIdx.x;
  const u16* kb = qkv + DM_;
  const u16* vb = qkv + 2*DM_;
  #pragma unroll
  for (int r = 0; r < 2; r++) {
    int idx = r*256 + t;
    int sr = idx >> 3;
    int c  = (idx & 7) * 8;
    int sg = s0 + sr;
    size_t base = ((size_t)(b*L_ + sg)) * QLD_ + h*DH_ + c;
    uint4 kk = *(const uint4*)(kb + base);
    uint4 vv = *(const uint4*)(vb + base);
    float mk = mask[b*L_ + sg];
    const u16* kp = (const u16*)&kk;
    const u16* vp = (const u16*)&vv;
    #pragma unroll
    for (int j = 0; j < 8; j++) {
      sK[sr*64 + c + j] = b2f(kp[j]) * mk;
      sV[sr*64 + c + j] = b2f(vp[j]);
    }
  }
  __syncthreads();
  const int m0 = (t >> 4) * 4;
  const int d0 = (t & 15) * 4;
  float acc[4][4] = {{0.f}};
  float ks[4] = {0.f, 0.f, 0.f, 0.f};
  for (int s = 0; s < 64; s++) {
    float4 vm = *(const float4*)(sV + s*64 + m0);
    float4 kk = *(const float4*)(sK + s*64 + d0);
    float vmv[4] = {vm.x, vm.y, vm.z, vm.w};
    float kkv[4] = {kk.x, kk.y, kk.z, kk.w};
    #pragma unroll
    for (int i = 0; i < 4; i++)
      #pragma unroll
      for (int j = 0; j < 4; j++) acc[i][j] += vmv[i] * kkv[j];
    if (t < 16) { ks[0] += kkv[0]; ks[1] += kkv[1]; ks[2] += kkv[2]; ks[3] += kkv[3]; }
  }
  float* o = kvp + ((size_t)bh*NCH_ + blockIdx.y) * 4096;
  #pragma unroll
  for (int i = 0; i < 4; i++) {
    float4 wv = {acc[i][0], acc[i][1], acc[i][2], acc[i][3]};
    *(float4*)(o + (m0 + i)*64 + d0) = wv;
  }
  if (t < 16) {
    float* ko = ksp + ((size_t)bh*NCH_ + blockIdx.y) * 64;
    #pragma unroll
    for (int j = 0; j < 4; j++) ko[d0 + j] = ks[j];
  }
}

// ---------------- KV stage 2: reduce over chunks ----------------
__global__ __launch_bounds__(256) void kv_reduce(
    const float* __restrict__ kvp, const float* __restrict__ ksp,
    float* __restrict__ kv, float* __restrict__ ksum)
{
  const int bh = blockIdx.x;
  const int i = blockIdx.y * 256 + threadIdx.x;
  float s = 0.f;
  #pragma unroll 8
  for (int c = 0; c < NCH_; c++) s += kvp[((size_t)bh*NCH_ + c)*4096 + i];
  kv[(size_t)bh*4096 + i] = s;
  if (blockIdx.y == 0 && threadIdx.x < 64) {
    float q = 0.f;
    #pragma unroll 8
    for (int c = 0; c < NCH_; c++) q += ksp[((size_t)bh*NCH_ + c)*64 + threadIdx.x];
    ksum[bh*64 + threadIdx.x] = q;
  }
}

// ---------------- attn: a[l,h,m] = Z * sum_d Q[l,h,d]*KV[h,m,d] (MFMA) ----------------
__global__ __launch_bounds__(256) void attn_av(
    const u16* __restrict__ qkv, const float* __restrict__ kv,
    const float* __restrict__ ksum, u16* __restrict__ ab)
{
  __shared__ alignas(16) u16 sQ[128*72];
  __shared__ alignas(16) u16 sKV[64*72];
  __shared__ float sKs[64];
  __shared__ float sZ[128];
  const int bh = blockIdx.x;
  const int b = bh / H_, h = bh % H_;
  const int l0 = blockIdx.y * 128;
  const int t = threadIdx.x;
  const int lane = t & 63;
  const int w = t >> 6;
  // stage KV (f32 -> bf16)
  for (int i = t; i < 4096; i += 256)
    sKV[(i >> 6)*72 + (i & 63)] = f2b(kv[(size_t)bh*4096 + i]);
  if (t < 64) sKs[t] = ksum[bh*64 + t];
  // stage Q (bf16, from fused qkv)
  #pragma unroll
  for (int r = 0; r < 4; r++) {
    int idx = r*256 + t;
    int s = idx >> 3;
    int c = (idx & 7) * 8;
    *(uint4*)(sQ + s*72 + c) =
        *(const uint4*)(qkv + ((size_t)(b*L_ + l0 + s)) * QLD_ + h*DH_ + c);
  }
  __syncthreads();
  // Z per row: 2 threads/row
  {
    int row = t >> 1, half = t & 1;
    float zd = 0.f;
    #pragma unroll
    for (int ch = 0; ch < 4; ch++) {
      bf16x8 qv = *(const bf16x8*)(sQ + row*72 + half*32 + ch*8);
      #pragma unroll
      for (int j = 0; j < 8; j++) zd += (float)qv[j] * sKs[half*32 + ch*8 + j];
    }
    zd += __shfl_xor(zd, 1, 64);
    if (half == 0) sZ[row] = 1.f / (zd + ATT_EPS_);
  }
  // MFMA: wave w -> rows w*32..w*32+31, cols 0..63
  const int lr = lane & 15, lk = (lane >> 4) * 8;
  f32x4 acc[2][4];
  #pragma unroll
  for (int m = 0; m < 2; m++)
    #pragma unroll
    for (int n = 0; n < 4; n++) acc[m][n] = (f32x4){0.f,0.f,0.f,0.f};
  #pragma unroll
  for (int kk = 0; kk < 2; kk++) {
    bf16x8 af[2], bv[4];
    #pragma unroll
    for (int m = 0; m < 2; m++) af[m] = *(const bf16x8*)(sQ + (w*32 + m*16 + lr)*72 + kk*32 + lk);
    #pragma unroll
    for (int n = 0; n < 4; n++) bv[n] = *(const bf16x8*)(sKV + (n*16 + lr)*72 + kk*32 + lk);
    #pragma unroll
    for (int m = 0; m < 2; m++)
      #pragma unroll
      for (int n = 0; n < 4; n++)
        acc[m][n] = __builtin_amdgcn_mfma_f32_16x16x32_bf16(af[m], bv[n], acc[m][n], 0, 0, 0);
  }
  __syncthreads();   // sZ visible
  #pragma unroll
  for (int m = 0; m < 2; m++) {
    const int row_l = w*32 + m*16 + (lane >> 4) * 4;
    #pragma unroll
    for (int n = 0; n < 4; n++) {
      const int col = n*16 + lr;
      #pragma unroll
      for (int r = 0; r < 4; r++) {
        float v = acc[m][n][r] * sZ[row_l + r];
        ab[((size_t)(b*L_ + l0 + row_l + r)) * DM_ + h*DH_ + col] = f2b(v);
      }
    }
  }
}

// ---------------- final copy ----------------
__global__ __launch_bounds__(256) void copyf4(const float4* __restrict__ in,
                                              float4* __restrict__ out, int n4) {
  int i = blockIdx.x * 256 + threadIdx.x;
  if (i < n4) out[i] = in[i];
}

extern "C" void kernel_launch(void* const* d_in, const int* in_sizes, int n_in,
                              void* d_out, int out_size, void* d_ws, size_t ws_size,
                              hipStream_t stream)
{
  const int*   ids  = (const int*)d_in[0];
  const float* mask = (const float*)d_in[1];
  const int*   tts  = (const int*)d_in[2];
  const float* we   = (const float*)d_in[3];
  const float* pe   = (const float*)d_in[4];
  const float* te   = (const float*)d_in[5];
  const float* elw  = (const float*)d_in[6];
  const float* elb  = (const float*)d_in[7];
  const float* Wq   = (const float*)d_in[8];
  const float* bq   = (const float*)d_in[9];
  const float* Wk   = (const float*)d_in[10];
  const float* bk   = (const float*)d_in[11];
  const float* Wv   = (const float*)d_in[12];
  const float* bv   = (const float*)d_in[13];
  const float* Wo   = (const float*)d_in[14];
  const float* bo   = (const float*)d_in[15];
  const float* l1w  = (const float*)d_in[16];
  const float* l1b  = (const float*)d_in[17];
  const float* W1   = (const float*)d_in[18];
  const float* b1   = (const float*)d_in[19];
  const float* W2   = (const float*)d_in[20];
  const float* b2   = (const float*)d_in[21];
  const float* l2w  = (const float*)d_in[22];
  const float* l2b  = (const float*)d_in[23];

  char* p = (char*)d_ws;
  auto alloc = [&](size_t n) -> char* {
    char* r = p; p += (n + 255) & ~(size_t)255; return r;
  };
  const size_t SQ = (size_t)NL_ * DM_ * DM_;
  const size_t SF = (size_t)NL_ * DFF_ * DM_;
  u16*  wqkvb = (u16*)alloc((size_t)NL_ * QLD_ * DM_ * 2);
  u16*  wob   = (u16*)alloc(SQ * 2);
  u16*  w1b   = (u16*)alloc(SF * 2);
  u16*  w2b   = (u16*)alloc(SF * 2);
  float* bqkv = (float*)alloc((size_t)NL_ * QLD_ * 4);
  float* x32  = (float*)alloc((size_t)M_ * DM_ * 4);
  float* t32  = (float*)alloc((size_t)M_ * DM_ * 4);
  u16*  xb    = (u16*)alloc((size_t)M_ * DM_ * 2);
  u16*  qkv   = (u16*)alloc((size_t)M_ * QLD_ * 2);
  u16*  abuf  = (u16*)alloc((size_t)M_ * DM_ * 2);
  u16*  ybuf  = (u16*)alloc((size_t)M_ * DFF_ * 2);
  float* kvb  = (float*)alloc((size_t)(B_*H_*DH_*DH_ + B_*H_*DH_) * 4);
  float* ksm  = kvb + (size_t)B_*H_*DH_*DH_;
  float* ksp  = (float*)alloc((size_t)B_*H_*NCH_*DH_ * 4);
  // kv partials alias t32 (dead until the Wo GEMM): 8192*768*4 == 48*32*4096*4
  float* kvp  = t32;

  const int nq4 = (int)(SQ/4);
  cvt_bf16_qkv<<<(nq4+255)/256, 256, 0, stream>>>(Wq, wqkvb, 0);
  cvt_bf16_qkv<<<(nq4+255)/256, 256, 0, stream>>>(Wk, wqkvb, DM_);
  cvt_bf16_qkv<<<(nq4+255)/256, 256, 0, stream>>>(Wv, wqkvb, 2*DM_);
  cvt_bf16<<<nq4/256, 256, 0, stream>>>(Wo, wob, nq4);
  cvt_bf16<<<(int)(SF/4/256), 256, 0, stream>>>(W1, w1b, (int)(SF/4));
  cvt_bf16<<<(int)(SF/4/256), 256, 0, stream>>>(W2, w2b, (int)(SF/4));
  fuse_bias<<<(NL_*QLD_+255)/256, 256, 0, stream>>>(bq, bk, bv, bqkv);

  embed_ln<<<M_/4, 256, 0, stream>>>(ids, tts, we, pe, te, elw, elb, x32, xb);

  for (int il = 0; il < NL_; ++il) {
    const u16* wqkv = wqkvb + (size_t)il * QLD_ * DM_;
    const u16* wo = wob + (size_t)il * DM_ * DM_;
    const u16* w1 = w1b + (size_t)il * DFF_ * DM_;
    const u16* w2 = w2b + (size_t)il * DFF_ * DM_;

    gemm_gl<4><<<dim3(M_/128, QLD_/128), 256, 0, stream>>>(
        xb, wqkv, bqkv + (size_t)il*QLD_, qkv, nullptr, M_, QLD_, DM_, QLD_);

    kv_part<<<dim3(B_*H_, NCH_), 256, 0, stream>>>(qkv, mask, kvp, ksp);
    kv_reduce<<<dim3(B_*H_, 16), 256, 0, stream>>>(kvp, ksp, kvb, ksm);
    attn_av<<<dim3(B_*H_, L_/128), 256, 0, stream>>>(qkv, kvb, ksm, abuf);

    gemm_n64<<<dim3(M_/128, DM_/64), 256, 0, stream>>>(
        abuf, wo, bo + (size_t)il*DM_, t32, M_, DM_, DM_, DM_);
    ln_res<<<M_/4, 256, 0, stream>>>(x32, t32, l1w + (size_t)il*DM_, l1b + (size_t)il*DM_, xb, LN_EPS_);

    gemm_gl<2><<<dim3(M_/128, DFF_/128), 256, 0, stream>>>(
        xb, w1, b1 + (size_t)il*DFF_, ybuf, nullptr, M_, DFF_, DM_, DFF_);
    gemm_n64<<<dim3(M_/128, DM_/64), 256, 0, stream>>>(
        ybuf, w2, b2 + (size_t)il*DM_, t32, M_, DM_, DFF_, DM_);
    ln_res<<<M_/4, 256, 0, stream>>>(x32, t32, l2w + (size_t)il*DM_, l2b + (size_t)il*DM_, xb, LN_EPS_);
  }

  copyf4<<<(M_*DM_/4)/256, 256, 0, stream>>>((const float4*)x32, (float4*)d_out, M_*DM_/4);
}